// Round 1
// baseline (1144.135 us; speedup 1.0000x reference)
//
#include <hip/hip_runtime.h>
#include <hip/hip_bf16.h>
#include <cstdio>
#include <cstdint>

#define BATCH 4
#define SEQ   4096
#define CDIM  1024
#define NH    16
#define HS    64
#define NL    64
#define MROWS 16384
#define N3    3072
#define KDIM  1024
#define KT_N  48   // K' = 3*1024 / 64

typedef __bf16 bf16_t;
typedef bf16_t bf16x8 __attribute__((ext_vector_type(8)));
typedef float  f32x4  __attribute__((ext_vector_type(4)));

__device__ __forceinline__ void gld_lds16(const void* g, void* l)
{
    __builtin_amdgcn_global_load_lds((__attribute__((address_space(1))) void*)(void*)g,
                                     (__attribute__((address_space(3))) void*)l,
                                     16, 0, 0);
}

// ---------- W transpose + hi/lo bf16 split: dst[n][k] = split(src[k][n]) ----------
__global__ __launch_bounds__(256) void transpose_split(const float* __restrict__ src,
                                                       bf16_t* __restrict__ dhi,
                                                       bf16_t* __restrict__ dlo,
                                                       int K, int N)
{
    __shared__ float tile[64][65];
    int n0 = blockIdx.x * 64, k0 = blockIdx.y * 64;
    for (int idx = threadIdx.x; idx < 4096; idx += 256) {
        int rk = idx >> 6, cn = idx & 63;
        tile[rk][cn] = src[(size_t)(k0 + rk) * N + n0 + cn];
    }
    __syncthreads();
    for (int idx = threadIdx.x; idx < 4096; idx += 256) {
        int rn = idx >> 6, ck = idx & 63;
        float v = tile[ck][rn];
        bf16_t hh = (bf16_t)v;
        size_t o = (size_t)(n0 + rn) * K + k0 + ck;
        dhi[o] = hh;
        dlo[o] = (bf16_t)(v - (float)hh);
    }
}

// ---------- x (fp32) -> hi/lo bf16 split, vectorized ----------
__global__ __launch_bounds__(256) void split_x(const float* __restrict__ src,
                                               bf16_t* __restrict__ dhi,
                                               bf16_t* __restrict__ dlo)
{
    size_t i = ((size_t)blockIdx.x * 256 + threadIdx.x) * 8;
    f32x4 a = *(const f32x4*)(src + i);
    f32x4 b = *(const f32x4*)(src + i + 4);
    bf16x8 h, l;
    #pragma unroll
    for (int j = 0; j < 4; j++) {
        bf16_t hh = (bf16_t)a[j]; h[j] = hh; l[j] = (bf16_t)(a[j] - (float)hh);
    }
    #pragma unroll
    for (int j = 0; j < 4; j++) {
        bf16_t hh = (bf16_t)b[j]; h[4 + j] = hh; l[4 + j] = (bf16_t)(b[j] - (float)hh);
    }
    *(bf16x8*)(dhi + i) = h;
    *(bf16x8*)(dlo + i) = l;
}

// ---------- 256x256 8-phase MFMA GEMM over K'=3072 (split-bf16 as 3 K-passes) ----------
// A (M x 1024) split into Ahi/Alo bf16; B^T (N x 1024) split into Bhi/Blo.
// K-tile tt in [0,48): tt<16: Ahi*Bhi, 16..31: Ahi*Blo, 32..47: Alo*Bhi.
// LDS: [buf][mat A/B][khalf][256 rows][32 bf16] -> split-k layout: each khalf
// is a contiguous 16KB region (global_load_lds-compatible), and the MFMA
// fragment read (16 rows x 4 k-chunks) is conflict-free: quad=(row&1)*4+lk.
__global__ __launch_bounds__(512, 2) void gemm8(const bf16_t* __restrict__ Ahi,
                                                const bf16_t* __restrict__ Alo,
                                                const bf16_t* __restrict__ Bhi,
                                                const bf16_t* __restrict__ Blo,
                                                float* __restrict__ C0,
                                                float* __restrict__ Cq,
                                                float* __restrict__ Ck,
                                                float* __restrict__ Cv,
                                                int N, int mode)
{
    __shared__ __align__(16) bf16_t lds[2][2][2][256][32];   // 128 KiB

    int tid  = threadIdx.x;
    int lane = tid & 63, wv = tid >> 6;
    int wr = wv >> 2, wc = wv & 3;          // 2M x 4N wave grid
    int lm = lane & 15, lk = lane >> 4;

    // bijective XCD swizzle (nwg % 8 == 0 for both launches)
    int nbx  = N >> 8;
    int flat = blockIdx.y * nbx + blockIdx.x;
    int nwg  = nbx * (int)gridDim.y;
    int cpx  = nwg >> 3;
    int swzb = (flat & 7) * cpx + (flat >> 3);
    int m0 = (swzb / nbx) << 8;
    int n0 = (swzb % nbx) << 8;

    // staging: per half-stage each wave issues 2 x global_load_lds (1KB each).
    // load j covers rows [wv*32 + j*16, +16), lane -> row += lane>>2, chunk = lane&3
    int wrow0 = wv << 5;
    int wrow1 = wrow0 + 16;
    int srow  = lane >> 2;
    int ssc8  = (lane & 3) << 3;
    size_t ga0 = (size_t)(m0 + wrow0 + srow) * KDIM + ssc8;
    size_t ga1 = (size_t)(m0 + wrow1 + srow) * KDIM + ssc8;
    size_t gb0 = (size_t)(n0 + wrow0 + srow) * KDIM + ssc8;
    size_t gb1 = (size_t)(n0 + wrow1 + srow) * KDIM + ssc8;

    auto stageA = [&](int tt, int kh) {
        const bf16_t* s = (tt < 32) ? Ahi : Alo;
        int kcol = ((tt & 15) << 6) + (kh << 5);
        int buf  = tt & 1;
        gld_lds16(s + ga0 + kcol, &lds[buf][0][kh][wrow0][0]);
        gld_lds16(s + ga1 + kcol, &lds[buf][0][kh][wrow1][0]);
    };
    auto stageB = [&](int tt, int kh) {
        const bf16_t* s = (tt < 16 || tt >= 32) ? Bhi : Blo;
        int kcol = ((tt & 15) << 6) + (kh << 5);
        int buf  = tt & 1;
        gld_lds16(s + gb0 + kcol, &lds[buf][1][kh][wrow0][0]);
        gld_lds16(s + gb1 + kcol, &lds[buf][1][kh][wrow1][0]);
    };

    f32x4 acc[8][4] = {};

    // prologue: prime pipeline; invariant entering t=0:
    // in flight = {(0)Ak1,(0)Bk1,(1)Ak0,(1)Bk0} (8 loads)
    stageA(0, 0); stageB(0, 0);
    stageA(0, 1); stageB(0, 1);
    stageA(1, 0); stageB(1, 0);
    asm volatile("s_waitcnt vmcnt(8)" ::: "memory");
    __builtin_amdgcn_s_barrier();

    for (int t = 0; t < KT_N; ++t) {
        int buf  = t & 1;
        int arow = wr * 128 + lm;
        int brow = wc * 64 + lm;
        int kc8  = lk * 8;
        bf16x8 afr[4], bfr[4];

        // ---- Phase 0: ksub 0, m-frags 0..3 (+ B frags ks0) ----
        #pragma unroll
        for (int i = 0; i < 4; i++)
            afr[i] = *(const bf16x8*)&lds[buf][0][0][arow + i * 16][kc8];
        #pragma unroll
        for (int j = 0; j < 4; j++)
            bfr[j] = *(const bf16x8*)&lds[buf][1][0][brow + j * 16][kc8];
        if (t + 1 < KT_N) stageA(t + 1, 1);
        __builtin_amdgcn_s_barrier();
        asm volatile("s_waitcnt lgkmcnt(0)" ::: "memory");
        __builtin_amdgcn_sched_barrier(0);
        __builtin_amdgcn_s_setprio(1);
        #pragma unroll
        for (int i = 0; i < 4; i++)
            #pragma unroll
            for (int j = 0; j < 4; j++)
                acc[i][j] = __builtin_amdgcn_mfma_f32_16x16x32_bf16(afr[i], bfr[j], acc[i][j], 0, 0, 0);
        __builtin_amdgcn_s_setprio(0);
        __builtin_amdgcn_sched_barrier(0);
        __builtin_amdgcn_s_barrier();

        // ---- Phase 1: ksub 0, m-frags 4..7 ----
        #pragma unroll
        for (int i = 0; i < 4; i++)
            afr[i] = *(const bf16x8*)&lds[buf][0][0][arow + (i + 4) * 16][kc8];
        if (t + 1 < KT_N) stageB(t + 1, 1);
        __builtin_amdgcn_s_barrier();
        asm volatile("s_waitcnt lgkmcnt(0)" ::: "memory");
        __builtin_amdgcn_sched_barrier(0);
        __builtin_amdgcn_s_setprio(1);
        #pragma unroll
        for (int i = 0; i < 4; i++)
            #pragma unroll
            for (int j = 0; j < 4; j++)
                acc[i + 4][j] = __builtin_amdgcn_mfma_f32_16x16x32_bf16(afr[i], bfr[j], acc[i + 4][j], 0, 0, 0);
        __builtin_amdgcn_s_setprio(0);
        __builtin_amdgcn_sched_barrier(0);
        // W_mid: retire (t)Ak1,(t)Bk1 (issued during t-1 P0/P1)
        if (t + 1 < KT_N) { asm volatile("s_waitcnt vmcnt(8)" ::: "memory"); }
        else              { asm volatile("s_waitcnt vmcnt(0)" ::: "memory"); }
        __builtin_amdgcn_s_barrier();

        // ---- Phase 2: ksub 1, m-frags 0..3 (+ B frags ks1) ----
        #pragma unroll
        for (int i = 0; i < 4; i++)
            afr[i] = *(const bf16x8*)&lds[buf][0][1][arow + i * 16][kc8];
        #pragma unroll
        for (int j = 0; j < 4; j++)
            bfr[j] = *(const bf16x8*)&lds[buf][1][1][brow + j * 16][kc8];
        if (t + 2 < KT_N) stageA(t + 2, 0);   // kh0 region of buf freed after P1
        __builtin_amdgcn_s_barrier();
        asm volatile("s_waitcnt lgkmcnt(0)" ::: "memory");
        __builtin_amdgcn_sched_barrier(0);
        __builtin_amdgcn_s_setprio(1);
        #pragma unroll
        for (int i = 0; i < 4; i++)
            #pragma unroll
            for (int j = 0; j < 4; j++)
                acc[i][j] = __builtin_amdgcn_mfma_f32_16x16x32_bf16(afr[i], bfr[j], acc[i][j], 0, 0, 0);
        __builtin_amdgcn_s_setprio(0);
        __builtin_amdgcn_sched_barrier(0);
        __builtin_amdgcn_s_barrier();

        // ---- Phase 3: ksub 1, m-frags 4..7 ----
        #pragma unroll
        for (int i = 0; i < 4; i++)
            afr[i] = *(const bf16x8*)&lds[buf][0][1][arow + (i + 4) * 16][kc8];
        if (t + 2 < KT_N) stageB(t + 2, 0);
        __builtin_amdgcn_s_barrier();
        asm volatile("s_waitcnt lgkmcnt(0)" ::: "memory");
        __builtin_amdgcn_sched_barrier(0);
        __builtin_amdgcn_s_setprio(1);
        #pragma unroll
        for (int i = 0; i < 4; i++)
            #pragma unroll
            for (int j = 0; j < 4; j++)
                acc[i + 4][j] = __builtin_amdgcn_mfma_f32_16x16x32_bf16(afr[i], bfr[j], acc[i + 4][j], 0, 0, 0);
        __builtin_amdgcn_s_setprio(0);
        __builtin_amdgcn_sched_barrier(0);
        // W_end: retire (t+1)Ak0,(t+1)Bk0 (issued during t-1 P2/P3)
        if (t + 2 < KT_N)      { asm volatile("s_waitcnt vmcnt(8)" ::: "memory"); }
        else if (t + 1 < KT_N) { asm volatile("s_waitcnt vmcnt(4)" ::: "memory"); }
        __builtin_amdgcn_s_barrier();
    }

    // ---- epilogue: C/D layout col=lane&15, row=(lane>>4)*4+reg ----
    if (mode == 0) {
        #pragma unroll
        for (int fm = 0; fm < 8; fm++) {
            int grow0 = m0 + wr * 128 + fm * 16 + lk * 4;
            #pragma unroll
            for (int fn = 0; fn < 4; fn++) {
                int gcol = n0 + wc * 64 + fn * 16 + lm;
                #pragma unroll
                for (int reg = 0; reg < 4; reg++)
                    C0[(size_t)(grow0 + reg) * N + gcol] = acc[fm][fn][reg];
            }
        }
    } else {
        #pragma unroll
        for (int fm = 0; fm < 8; fm++) {
            int grow0 = m0 + wr * 128 + fm * 16 + lk * 4;
            #pragma unroll
            for (int fn = 0; fn < 4; fn++) {
                int n = n0 + wc * 64 + fn * 16 + lm;
                float* dst; int nn;
                if (n < 1024)      { dst = Cq; nn = n; }
                else if (n < 2048) { dst = Ck; nn = n - 1024; }
                else               { dst = Cv; nn = n - 2048; }
                int hh = nn >> 6, d = nn & 63;
                #pragma unroll
                for (int reg = 0; reg < 4; reg++) {
                    int m = grow0 + reg;
                    int b = m >> 12, tt2 = m & 4095;
                    dst[(((size_t)(b * NH + hh)) * SEQ + tt2) * HS + d] = acc[fm][fn][reg];
                }
            }
        }
    }
}

// ---------------- landmarks ----------------
__global__ __launch_bounds__(256) void landmark_kernel(const float* __restrict__ q,
                                                       const float* __restrict__ k,
                                                       float* __restrict__ ql,
                                                       float* __restrict__ kl)
{
    int idx = blockIdx.x * 256 + threadIdx.x;
    int d = idx & 63, l = (idx >> 6) & 63, bh = idx >> 12;
    const float* qp = q + (((size_t)bh * SEQ) + l * 64) * HS + d;
    const float* kp = k + (((size_t)bh * SEQ) + l * 64) * HS + d;
    float sq = 0.f, sk = 0.f;
    for (int t = 0; t < 64; t++) { sq += qp[t * HS]; sk += kp[t * HS]; }
    ql[idx] = sq * (1.0f / 64.0f);
    kl[idx] = sk * (1.0f / 64.0f);
}

// ---------------- pinv (all-LDS Newton-Schulz) ----------------
__global__ __launch_bounds__(256) void pinv_kernel(const float* __restrict__ ql,
                                                   const float* __restrict__ kl,
                                                   float* __restrict__ Pbuf)
{
    int bh = blockIdx.x;
    __shared__ float Asm[64][65], V[64][65], KV[64][65], Tb[64][65], Ub[64][65];
    __shared__ float denom_s;
    int tid = threadIdx.x;
    int r = tid >> 2, c0 = (tid & 3) << 4;
    const float* qlp = ql + (size_t)bh * 4096;
    const float* klp = kl + (size_t)bh * 4096;

    for (int j = 0; j < 16; j++) {
        int cc = c0 + j; float acc = 0.f;
        for (int d = 0; d < 64; d++) acc += qlp[r * 64 + d] * klp[cc * 64 + d];
        Tb[r][cc] = acc;
    }
    __syncthreads();
    {
        float m = -1e30f;
        for (int j = 0; j < 64; j++) m = fmaxf(m, Tb[r][j]);
        float s = 0.f;
        for (int j = 0; j < 64; j++) s += expf(Tb[r][j] - m);
        float inv = 1.0f / s;
        for (int j = 0; j < 16; j++) {
            int cc = c0 + j;
            Asm[r][cc] = expf(Tb[r][cc] - m) * inv;
        }
    }
    __syncthreads();
    if (tid < 64) {
        float cs = 0.f;
        for (int i = 0; i < 64; i++) cs += Asm[i][tid];
        Ub[0][tid] = cs;
    }
    __syncthreads();
    if (tid == 0) {
        float mx = Ub[0][0];
        for (int j = 1; j < 64; j++) mx = fmaxf(mx, Ub[0][j]);
        denom_s = mx;
    }
    __syncthreads();
    for (int j = 0; j < 16; j++) { int cc = c0 + j; V[r][cc] = Asm[cc][r] / denom_s; }
    __syncthreads();

    float facc[16];
    for (int it = 0; it < 6; it++) {
        for (int j = 0; j < 16; j++) facc[j] = 0.f;
        for (int kx = 0; kx < 64; kx++) {
            float a = Asm[r][kx];
            for (int j = 0; j < 16; j++) facc[j] += a * V[kx][c0 + j];
        }
        for (int j = 0; j < 16; j++) KV[r][c0 + j] = facc[j];
        __syncthreads();
        for (int j = 0; j < 16; j++) {
            int cc = c0 + j;
            Tb[r][cc] = (r == cc ? 7.0f : 0.0f) - KV[r][cc];
        }
        __syncthreads();
        for (int j = 0; j < 16; j++) facc[j] = 0.f;
        for (int kx = 0; kx < 64; kx++) {
            float a = KV[r][kx];
            for (int j = 0; j < 16; j++) facc[j] += a * Tb[kx][c0 + j];
        }
        for (int j = 0; j < 16; j++) Ub[r][c0 + j] = facc[j];
        __syncthreads();
        for (int j = 0; j < 16; j++) {
            int cc = c0 + j;
            Tb[r][cc] = (r == cc ? 15.0f : 0.0f) - Ub[r][cc];
        }
        __syncthreads();
        for (int j = 0; j < 16; j++) facc[j] = 0.f;
        for (int kx = 0; kx < 64; kx++) {
            float a = KV[r][kx];
            for (int j = 0; j < 16; j++) facc[j] += a * Tb[kx][c0 + j];
        }
        for (int j = 0; j < 16; j++) Ub[r][c0 + j] = facc[j];
        __syncthreads();
        for (int j = 0; j < 16; j++) {
            int cc = c0 + j;
            Tb[r][cc] = (r == cc ? 13.0f : 0.0f) - Ub[r][cc];
        }
        __syncthreads();
        for (int j = 0; j < 16; j++) facc[j] = 0.f;
        for (int kx = 0; kx < 64; kx++) {
            float a = V[r][kx];
            for (int j = 0; j < 16; j++) facc[j] += a * Tb[kx][c0 + j];
        }
        for (int j = 0; j < 16; j++) Ub[r][c0 + j] = facc[j];
        __syncthreads();
        for (int j = 0; j < 16; j++) V[r][c0 + j] = 0.25f * Ub[r][c0 + j];
        __syncthreads();
    }
    for (int j = 0; j < 16; j++)
        Pbuf[(size_t)bh * 4096 + r * 64 + c0 + j] = V[r][c0 + j];
}

// ---------------- N path phase 1: per (bh, 256-wide t-chunk) partials ----------------
#define NVP 68
__global__ __launch_bounds__(256) void nv_partial(const float* __restrict__ ql,
                                                  const float* __restrict__ k,
                                                  const float* __restrict__ v,
                                                  float* __restrict__ pm,
                                                  float* __restrict__ ps,
                                                  float* __restrict__ pacc)
{
    int bh = blockIdx.y;
    int c0 = blockIdx.x;
    int tid = threadIdx.x;
    int rg = tid >> 4, tg = tid & 15;
    __shared__ float qlT[64][NVP];
    __shared__ float kT[64][NVP];
    __shared__ float vch[64][NVP];
    __shared__ float pch[64][NVP];

    {
        const float* qp = ql + (size_t)bh * 4096;
        for (int i = tid; i < 4096; i += 256) {
            int l = i >> 6, d = i & 63;
            qlT[d][l] = qp[i];
        }
    }

    float m_r[4], s_r[4];
    float acc[4][4];
    #pragma unroll
    for (int i = 0; i < 4; i++) {
        m_r[i] = -1e30f; s_r[i] = 0.f;
        #pragma unroll
        for (int j = 0; j < 4; j++) acc[i][j] = 0.f;
    }

    for (int sc = 0; sc < 4; sc++) {
        __syncthreads();
        const float* kp = k + ((size_t)bh * SEQ + c0 * 256 + sc * 64) * HS;
        const float* vp = v + ((size_t)bh * SEQ + c0 * 256 + sc * 64) * HS;
        for (int i = tid; i < 4096; i += 256) {
            int tt = i >> 6, d = i & 63;
            kT[d][tt]  = kp[i];
            vch[tt][d] = vp[i];
        }
        __syncthreads();

        float s[4][4] = {};
        #pragma unroll 4
        for (int dd = 0; dd < 64; dd++) {
            f32x4 a = *(const f32x4*)&qlT[dd][rg * 4];
            f32x4 b = *(const f32x4*)&kT[dd][tg * 4];
            #pragma unroll
            for (int i = 0; i < 4; i++)
                #pragma unroll
                for (int j = 0; j < 4; j++) s[i][j] += a[i] * b[j];
        }

        #pragma unroll
        for (int i = 0; i < 4; i++) {
            float tmax = fmaxf(fmaxf(s[i][0], s[i][1]), fmaxf(s[i][2], s[i][3]));
            #pragma unroll
            for (int off = 1; off < 16; off <<= 1)
                tmax = fmaxf(tmax, __shfl_xor(tmax, off, 64));
            float mnew = fmaxf(m_r[i], tmax);
            float alpha = expf(m_r[i] - mnew);
            m_r[i] = mnew;
            float psum = 0.f;
            #pragma unroll
            for (int j = 0; j < 4; j++) {
                float p = expf(s[i][j] - mnew);
                s[i][j] = p;
                psum += p;
            }
            #pragma unroll
            for (int off = 1; off < 16; off <<= 1)
                psum += __shfl_xor(psum, off, 64);
            s_r[i] = s_r[i] * alpha + psum;
            *(f32x4*)&pch[rg * 4 + i][tg * 4] = *(f32x4*)&s[i][0];
            #pragma unroll
            for (int j = 0; j < 4; j++) acc[i][j] *= alpha;
        }
        __syncthreads();

        #pragma unroll 2
        for (int tt = 0; tt < 64; tt++) {
            f32x4 vv = *(const f32x4*)&vch[tt][tg * 4];
            float p0 = pch[rg * 4 + 0][tt];
            float p1 = pch[rg * 4 + 1][tt];
            float p2 = pch[rg * 4 + 2][tt];
            float p3 = pch[rg * 4 + 3][tt];
            #pragma unroll
            for (int j = 0; j < 4; j++) {
                acc[0][j] += p0 * vv[j];
                acc[1][j] += p1 * vv[j];
                acc[2][j] += p2 * vv[j];
                acc[3][j] += p3 * vv[j];
            }
        }
    }

    float* paccp = pacc + ((((size_t)bh * 16 + c0) * 64) + rg * 4) * 64 + tg * 4;
    #pragma unroll
    for (int i = 0; i < 4; i++)
        *(f32x4*)&paccp[(size_t)i * 64] = *(f32x4*)&acc[i][0];
    if (tg == 0) {
        #pragma unroll
        for (int i = 0; i < 4; i++) {
            pm[((size_t)bh * 16 + c0) * 64 + rg * 4 + i] = m_r[i];
            ps[((size_t)bh * 16 + c0) * 64 + rg * 4 + i] = s_r[i];
        }
    }
}

// ---------------- N path phase 2: combine 16 chunk partials ----------------
__global__ __launch_bounds__(256) void nv_combine(const float* __restrict__ pm,
                                                  const float* __restrict__ ps,
                                                  const float* __restrict__ pacc,
                                                  float* __restrict__ Nv)
{
    int bh = blockIdx.x;
    int tid = threadIdx.x;
    int l = tid >> 2, dq = tid & 3;
    float m16[16];
    float gm = -1e30f;
    #pragma unroll
    for (int c = 0; c < 16; c++) {
        m16[c] = pm[((size_t)bh * 16 + c) * 64 + l];
        gm = fmaxf(gm, m16[c]);
    }
    float gs = 0.f;
    float e16[16];
    #pragma unroll
    for (int c = 0; c < 16; c++) {
        float e = expf(m16[c] - gm);
        e16[c] = e;
        gs += ps[((size_t)bh * 16 + c) * 64 + l] * e;
    }
    f32x4 a[4] = {};
    for (int c = 0; c < 16; c++) {
        float e = e16[c];
        const float* pp = pacc + (((size_t)bh * 16 + c) * 64 + l) * 64 + dq * 16;
        #pragma unroll
        for (int i = 0; i < 4; i++) {
            f32x4 t = *(const f32x4*)&pp[4 * i];
            a[i] += e * t;
        }
    }
    float inv = 1.0f / gs;
    float* np = Nv + (size_t)bh * 4096 + l * 64 + dq * 16;
    #pragma unroll
    for (int i = 0; i < 4; i++) {
        f32x4 o = a[i] * inv;
        *(f32x4*)&np[4 * i] = o;
    }
}

// ---------------- PNv = P @ Nv ----------------
__global__ __launch_bounds__(256) void pnv_kernel(const float* __restrict__ P,
                                                  const float* __restrict__ Nv,
                                                  float* __restrict__ PNv)
{
    int bh = blockIdx.x, tid = threadIdx.x;
    __shared__ float pb[64][65], nb[64][65];
    for (int i = tid; i < 4096; i += 256) {
        pb[i >> 6][i & 63] = P[(size_t)bh * 4096 + i];
        nb[i >> 6][i & 63] = Nv[(size_t)bh * 4096 + i];
    }
    __syncthreads();
    int r = tid >> 2, c0 = (tid & 3) << 4;
    for (int j = 0; j < 16; j++) {
        int cc = c0 + j; float acc = 0.f;
        for (int kx = 0; kx < 64; kx++) acc += pb[r][kx] * nb[kx][cc];
        PNv[(size_t)bh * 4096 + r * 64 + cc] = acc;
    }
}

// ---------------- y = softmax(q @ kl^T) @ PNv -> hi/lo bf16 (B,T,C) ----------------
__global__ __launch_bounds__(256) void y_kernel(const float* __restrict__ q,
                                                const float* __restrict__ kl,
                                                const float* __restrict__ PNv,
                                                bf16_t* __restrict__ yhi,
                                                bf16_t* __restrict__ ylo)
{
    int bh = blockIdx.y;
    int t0 = blockIdx.x * 64;
    int tid = threadIdx.x;
    __shared__ float qch[64][65], klb[64][65], pnv[64][65], srow[64][65];
    const float* qp = q + ((size_t)bh * SEQ + t0) * HS;
    for (int i = tid; i < 4096; i += 256) {
        qch[i >> 6][i & 63] = qp[i];
        klb[i >> 6][i & 63] = kl[(size_t)bh * 4096 + i];
        pnv[i >> 6][i & 63] = PNv[(size_t)bh * 4096 + i];
    }
    __syncthreads();
    int t = tid >> 2, l0 = (tid & 3) << 4;
    for (int j = 0; j < 16; j++) {
        int l = l0 + j; float acc = 0.f;
        for (int d = 0; d < 64; d++) acc += qch[t][d] * klb[l][d];
        srow[t][l] = acc;
    }
    __syncthreads();
    float m = -1e30f;
    for (int l = 0; l < 64; l++) m = fmaxf(m, srow[t][l]);
    float s = 0.f;
    for (int l = 0; l < 64; l++) s += expf(srow[t][l] - m);
    float inv = 1.0f / s;
    int d0 = (tid & 3) << 4;
    float acc[16] = {};
    for (int l = 0; l < 64; l++) {
        float w = expf(srow[t][l] - m) * inv;
        for (int j = 0; j < 16; j++) acc[j] += w * pnv[l][d0 + j];
    }
    int b = bh >> 4, h = bh & 15;
    size_t o = ((size_t)(b * SEQ) + t0 + t) * CDIM + h * HS + d0;
    for (int j = 0; j < 16; j++) {
        float v = acc[j];
        bf16_t hh = (bf16_t)v;
        yhi[o + j] = hh;
        ylo[o + j] = (bf16_t)(v - (float)hh);
    }
}

// ---------------- launch ----------------
extern "C" void kernel_launch(void* const* d_in, const int* in_sizes, int n_in,
                              void* d_out, int out_size, void* d_ws, size_t ws_size,
                              hipStream_t stream)
{
    const float* x  = (const float*)d_in[0];
    const float* Wa = (const float*)d_in[1];
    const float* Wp = (const float*)d_in[2];
    float* out = (float*)d_out;
    float* W = (float*)d_ws;

    const size_t off_q    = 0;
    const size_t off_k    = 16777216;
    const size_t off_v    = 33554432;
    const size_t off_ql   = 50331648;
    const size_t off_kl   = off_ql + 262144;
    const size_t off_P    = off_kl + 262144;
    const size_t off_Nv   = off_P  + 262144;
    const size_t off_PNv  = off_Nv + 262144;
    const size_t off_WatH = off_PNv + 262144;
    const size_t off_WatL = off_WatH + 1572864;
    const size_t off_WptH = off_WatL + 1572864;
    const size_t off_WptL = off_WptH + 524288;
    const size_t off_pm   = off_WptL + 524288;
    const size_t off_ps   = off_pm + 65536;
    const size_t off_pacc = off_ps + 65536;
    const size_t need = (off_pacc + 4194304) * sizeof(float);
    if (ws_size < need) {
        fprintf(stderr, "[nystrom] ws too small: have %zu need %zu\n", ws_size, need);
        return;
    }

    float* q    = W + off_q;
    float* k    = W + off_k;
    float* v    = W + off_v;
    float* ql   = W + off_ql;
    float* kl   = W + off_kl;
    float* P    = W + off_P;
    float* Nv   = W + off_Nv;
    float* PNv  = W + off_PNv;
    bf16_t* WatH = (bf16_t*)(W + off_WatH);
    bf16_t* WatL = (bf16_t*)(W + off_WatL);
    bf16_t* WptH = (bf16_t*)(W + off_WptH);
    bf16_t* WptL = (bf16_t*)(W + off_WptL);
    float* pm   = W + off_pm;
    float* ps   = W + off_ps;
    float* pacc = W + off_pacc;
    bf16_t* yhi = (bf16_t*)(W + off_k);       // alias k (dead after nv_partial)
    bf16_t* ylo = yhi + (size_t)MROWS * CDIM;
    // x split lives in d_out (dead as scratch until final proj GEMM writes it):
    // xhi+xlo = 2 * 16384*1024*2B = 64MB = out_size exactly.
    bf16_t* xhi = (bf16_t*)d_out;
    bf16_t* xlo = xhi + (size_t)MROWS * KDIM;

    transpose_split<<<dim3(N3 / 64, KDIM / 64), 256, 0, stream>>>(Wa, WatH, WatL, KDIM, N3);
    transpose_split<<<dim3(CDIM / 64, KDIM / 64), 256, 0, stream>>>(Wp, WptH, WptL, KDIM, CDIM);
    split_x<<<(MROWS * KDIM) / (256 * 8), 256, 0, stream>>>(x, xhi, xlo);
    gemm8<<<dim3(N3 / 256, MROWS / 256), 512, 0, stream>>>(xhi, xlo, WatH, WatL,
                                                           nullptr, q, k, v, N3, 1);
    landmark_kernel<<<262144 / 256, 256, 0, stream>>>(q, k, ql, kl);
    pinv_kernel<<<64, 256, 0, stream>>>(ql, kl, P);
    nv_partial<<<dim3(16, 64), 256, 0, stream>>>(ql, k, v, pm, ps, pacc);
    nv_combine<<<64, 256, 0, stream>>>(pm, ps, pacc, Nv);
    pnv_kernel<<<64, 256, 0, stream>>>(P, Nv, PNv);
    y_kernel<<<dim3(64, 64), 256, 0, stream>>>(q, kl, PNv, yhi, ylo);
    gemm8<<<dim3(CDIM / 256, MROWS / 256), 512, 0, stream>>>(yhi, ylo, WptH, WptL,
                                                             out, nullptr, nullptr, nullptr, CDIM, 0);
}

// Round 2
// 1090.776 us; speedup vs baseline: 1.0489x; 1.0489x over previous
//
#include <hip/hip_runtime.h>
#include <hip/hip_bf16.h>
#include <cstdio>
#include <cstdint>

#define BATCH 4
#define SEQ   4096
#define CDIM  1024
#define NH    16
#define HS    64
#define NL    64
#define MROWS 16384
#define N3    3072
#define KDIM  1024
#define KT_N  48   // K' = 3*1024 / 64

typedef __bf16 bf16_t;
typedef bf16_t bf16x8 __attribute__((ext_vector_type(8)));
typedef float  f32x4  __attribute__((ext_vector_type(4)));

__device__ __forceinline__ void gld_lds16(const void* g, void* l)
{
    __builtin_amdgcn_global_load_lds((__attribute__((address_space(1))) void*)(void*)g,
                                     (__attribute__((address_space(3))) void*)l,
                                     16, 0, 0);
}

// ---------- W transpose + hi/lo bf16 split: dst[n][k] = split(src[k][n]) ----------
__global__ __launch_bounds__(256) void transpose_split(const float* __restrict__ src,
                                                       bf16_t* __restrict__ dhi,
                                                       bf16_t* __restrict__ dlo,
                                                       int K, int N)
{
    __shared__ float tile[64][65];
    int n0 = blockIdx.x * 64, k0 = blockIdx.y * 64;
    for (int idx = threadIdx.x; idx < 4096; idx += 256) {
        int rk = idx >> 6, cn = idx & 63;
        tile[rk][cn] = src[(size_t)(k0 + rk) * N + n0 + cn];
    }
    __syncthreads();
    for (int idx = threadIdx.x; idx < 4096; idx += 256) {
        int rn = idx >> 6, ck = idx & 63;
        float v = tile[ck][rn];
        bf16_t hh = (bf16_t)v;
        size_t o = (size_t)(n0 + rn) * K + k0 + ck;
        dhi[o] = hh;
        dlo[o] = (bf16_t)(v - (float)hh);
    }
}

// ---------- x (fp32) -> hi/lo bf16 split, vectorized ----------
__global__ __launch_bounds__(256) void split_x(const float* __restrict__ src,
                                               bf16_t* __restrict__ dhi,
                                               bf16_t* __restrict__ dlo)
{
    size_t i = ((size_t)blockIdx.x * 256 + threadIdx.x) * 8;
    f32x4 a = *(const f32x4*)(src + i);
    f32x4 b = *(const f32x4*)(src + i + 4);
    bf16x8 h, l;
    #pragma unroll
    for (int j = 0; j < 4; j++) {
        bf16_t hh = (bf16_t)a[j]; h[j] = hh; l[j] = (bf16_t)(a[j] - (float)hh);
    }
    #pragma unroll
    for (int j = 0; j < 4; j++) {
        bf16_t hh = (bf16_t)b[j]; h[4 + j] = hh; l[4 + j] = (bf16_t)(b[j] - (float)hh);
    }
    *(bf16x8*)(dhi + i) = h;
    *(bf16x8*)(dlo + i) = l;
}

// ---------- 256x256 8-phase MFMA GEMM over K'=3072 (split-bf16 as 3 K-passes) ----------
// A (M x 1024) split into Ahi/Alo bf16; B^T (N x 1024) split into Bhi/Blo.
// K-tile tt in [0,48): tt<16: Ahi*Bhi, 16..31: Ahi*Blo, 32..47: Alo*Bhi.
// LDS: [buf][mat A/B][khalf][256 rows][32 bf16]; each khalf is a contiguous
// 16KB region (global_load_lds-compatible).
// T2 bank-conflict swizzle (both-sides, rule #21): LDS position (row, chunk cg)
// holds global k-chunk cg ^ ((row>>1)&3).
//  - stage: lane l serves row wrow+(l>>2) (wrow%16==0) -> source chunk
//    (l&3)^((l>>3)&3)  (lane-constant, folded into the address precompute)
//  - read: column chunk = lk ^ ((lm>>1)&3)  (loop-invariant per lane)
// Quad walk (4*row + cg) mod 8 then covers all 8 bank-quads over 16 rows ->
// conflict-free ds_read_b128 (matches old kernel's measured-0 pattern).
__global__ __launch_bounds__(512, 2) void gemm8(const bf16_t* __restrict__ Ahi,
                                                const bf16_t* __restrict__ Alo,
                                                const bf16_t* __restrict__ Bhi,
                                                const bf16_t* __restrict__ Blo,
                                                float* __restrict__ C0,
                                                float* __restrict__ Cq,
                                                float* __restrict__ Ck,
                                                float* __restrict__ Cv,
                                                int N, int mode)
{
    __shared__ __align__(16) bf16_t lds[2][2][2][256][32];   // 128 KiB

    int tid  = threadIdx.x;
    int lane = tid & 63, wv = tid >> 6;
    int wr = wv >> 2, wc = wv & 3;          // 2M x 4N wave grid
    int lm = lane & 15, lk = lane >> 4;

    // bijective XCD swizzle (nwg % 8 == 0 for both launches)
    int nbx  = N >> 8;
    int flat = blockIdx.y * nbx + blockIdx.x;
    int nwg  = nbx * (int)gridDim.y;
    int cpx  = nwg >> 3;
    int swzb = (flat & 7) * cpx + (flat >> 3);
    int m0 = (swzb / nbx) << 8;
    int n0 = (swzb % nbx) << 8;

    // staging: per half-stage each wave issues 2 x global_load_lds (1KB each).
    // load j covers rows [wv*32 + j*16, +16), lane -> row += lane>>2,
    // source chunk = (lane&3) ^ ((lane>>3)&3)  [T2 source pre-swizzle]
    int wrow0 = wv << 5;
    int wrow1 = wrow0 + 16;
    int srow  = lane >> 2;
    int ssc8  = (((lane & 3) ^ ((lane >> 3) & 3)) << 3);
    size_t ga0 = (size_t)(m0 + wrow0 + srow) * KDIM + ssc8;
    size_t ga1 = (size_t)(m0 + wrow1 + srow) * KDIM + ssc8;
    size_t gb0 = (size_t)(n0 + wrow0 + srow) * KDIM + ssc8;
    size_t gb1 = (size_t)(n0 + wrow1 + srow) * KDIM + ssc8;

    auto stageA = [&](int tt, int kh) {
        const bf16_t* s = (tt < 32) ? Ahi : Alo;
        int kcol = ((tt & 15) << 6) + (kh << 5);
        int buf  = tt & 1;
        gld_lds16(s + ga0 + kcol, &lds[buf][0][kh][wrow0][0]);
        gld_lds16(s + ga1 + kcol, &lds[buf][0][kh][wrow1][0]);
    };
    auto stageB = [&](int tt, int kh) {
        const bf16_t* s = (tt < 16 || tt >= 32) ? Bhi : Blo;
        int kcol = ((tt & 15) << 6) + (kh << 5);
        int buf  = tt & 1;
        gld_lds16(s + gb0 + kcol, &lds[buf][1][kh][wrow0][0]);
        gld_lds16(s + gb1 + kcol, &lds[buf][1][kh][wrow1][0]);
    };

    f32x4 acc[8][4] = {};

    // prologue: prime pipeline; invariant entering t=0:
    // in flight = {(0)Ak1,(0)Bk1,(1)Ak0,(1)Bk0} (8 loads)
    stageA(0, 0); stageB(0, 0);
    stageA(0, 1); stageB(0, 1);
    stageA(1, 0); stageB(1, 0);
    asm volatile("s_waitcnt vmcnt(8)" ::: "memory");
    __builtin_amdgcn_s_barrier();

    int arow = wr * 128 + lm;
    int brow = wc * 64 + lm;
    int kswz = 8 * (lk ^ ((lm >> 1) & 3));   // T2 read-side swizzled column

    for (int t = 0; t < KT_N; ++t) {
        int buf  = t & 1;
        bf16x8 afr[4], bfr[4];

        // ---- Phase 0: ksub 0, m-frags 0..3 (+ B frags ks0) ----
        #pragma unroll
        for (int i = 0; i < 4; i++)
            afr[i] = *(const bf16x8*)&lds[buf][0][0][arow + i * 16][kswz];
        #pragma unroll
        for (int j = 0; j < 4; j++)
            bfr[j] = *(const bf16x8*)&lds[buf][1][0][brow + j * 16][kswz];
        if (t + 1 < KT_N) stageA(t + 1, 1);
        __builtin_amdgcn_s_barrier();
        asm volatile("s_waitcnt lgkmcnt(0)" ::: "memory");
        __builtin_amdgcn_sched_barrier(0);
        __builtin_amdgcn_s_setprio(1);
        #pragma unroll
        for (int i = 0; i < 4; i++)
            #pragma unroll
            for (int j = 0; j < 4; j++)
                acc[i][j] = __builtin_amdgcn_mfma_f32_16x16x32_bf16(afr[i], bfr[j], acc[i][j], 0, 0, 0);
        __builtin_amdgcn_s_setprio(0);
        __builtin_amdgcn_sched_barrier(0);
        __builtin_amdgcn_s_barrier();

        // ---- Phase 1: ksub 0, m-frags 4..7 ----
        #pragma unroll
        for (int i = 0; i < 4; i++)
            afr[i] = *(const bf16x8*)&lds[buf][0][0][arow + (i + 4) * 16][kswz];
        if (t + 1 < KT_N) stageB(t + 1, 1);
        __builtin_amdgcn_s_barrier();
        asm volatile("s_waitcnt lgkmcnt(0)" ::: "memory");
        __builtin_amdgcn_sched_barrier(0);
        __builtin_amdgcn_s_setprio(1);
        #pragma unroll
        for (int i = 0; i < 4; i++)
            #pragma unroll
            for (int j = 0; j < 4; j++)
                acc[i + 4][j] = __builtin_amdgcn_mfma_f32_16x16x32_bf16(afr[i], bfr[j], acc[i + 4][j], 0, 0, 0);
        __builtin_amdgcn_s_setprio(0);
        __builtin_amdgcn_sched_barrier(0);
        // W_mid: retire (t)Ak1,(t)Bk1 (issued during t-1 P0/P1)
        if (t + 1 < KT_N) { asm volatile("s_waitcnt vmcnt(8)" ::: "memory"); }
        else              { asm volatile("s_waitcnt vmcnt(0)" ::: "memory"); }
        __builtin_amdgcn_s_barrier();

        // ---- Phase 2: ksub 1, m-frags 0..3 (+ B frags ks1) ----
        #pragma unroll
        for (int i = 0; i < 4; i++)
            afr[i] = *(const bf16x8*)&lds[buf][0][1][arow + i * 16][kswz];
        #pragma unroll
        for (int j = 0; j < 4; j++)
            bfr[j] = *(const bf16x8*)&lds[buf][1][1][brow + j * 16][kswz];
        if (t + 2 < KT_N) stageA(t + 2, 0);   // kh0 region of buf freed after P1
        __builtin_amdgcn_s_barrier();
        asm volatile("s_waitcnt lgkmcnt(0)" ::: "memory");
        __builtin_amdgcn_sched_barrier(0);
        __builtin_amdgcn_s_setprio(1);
        #pragma unroll
        for (int i = 0; i < 4; i++)
            #pragma unroll
            for (int j = 0; j < 4; j++)
                acc[i][j] = __builtin_amdgcn_mfma_f32_16x16x32_bf16(afr[i], bfr[j], acc[i][j], 0, 0, 0);
        __builtin_amdgcn_s_setprio(0);
        __builtin_amdgcn_sched_barrier(0);
        __builtin_amdgcn_s_barrier();

        // ---- Phase 3: ksub 1, m-frags 4..7 ----
        #pragma unroll
        for (int i = 0; i < 4; i++)
            afr[i] = *(const bf16x8*)&lds[buf][0][1][arow + (i + 4) * 16][kswz];
        if (t + 2 < KT_N) stageB(t + 2, 0);
        __builtin_amdgcn_s_barrier();
        asm volatile("s_waitcnt lgkmcnt(0)" ::: "memory");
        __builtin_amdgcn_sched_barrier(0);
        __builtin_amdgcn_s_setprio(1);
        #pragma unroll
        for (int i = 0; i < 4; i++)
            #pragma unroll
            for (int j = 0; j < 4; j++)
                acc[i + 4][j] = __builtin_amdgcn_mfma_f32_16x16x32_bf16(afr[i], bfr[j], acc[i + 4][j], 0, 0, 0);
        __builtin_amdgcn_s_setprio(0);
        __builtin_amdgcn_sched_barrier(0);
        // W_end: retire (t+1)Ak0,(t+1)Bk0 (issued during t-1 P2/P3)
        if (t + 2 < KT_N)      { asm volatile("s_waitcnt vmcnt(8)" ::: "memory"); }
        else if (t + 1 < KT_N) { asm volatile("s_waitcnt vmcnt(4)" ::: "memory"); }
        __builtin_amdgcn_s_barrier();
    }

    // ---- epilogue: C/D layout col=lane&15, row=(lane>>4)*4+reg ----
    if (mode == 0) {
        #pragma unroll
        for (int fm = 0; fm < 8; fm++) {
            int grow0 = m0 + wr * 128 + fm * 16 + lk * 4;
            #pragma unroll
            for (int fn = 0; fn < 4; fn++) {
                int gcol = n0 + wc * 64 + fn * 16 + lm;
                #pragma unroll
                for (int reg = 0; reg < 4; reg++)
                    C0[(size_t)(grow0 + reg) * N + gcol] = acc[fm][fn][reg];
            }
        }
    } else {
        #pragma unroll
        for (int fm = 0; fm < 8; fm++) {
            int grow0 = m0 + wr * 128 + fm * 16 + lk * 4;
            #pragma unroll
            for (int fn = 0; fn < 4; fn++) {
                int n = n0 + wc * 64 + fn * 16 + lm;
                float* dst; int nn;
                if (n < 1024)      { dst = Cq; nn = n; }
                else if (n < 2048) { dst = Ck; nn = n - 1024; }
                else               { dst = Cv; nn = n - 2048; }
                int hh = nn >> 6, d = nn & 63;
                #pragma unroll
                for (int reg = 0; reg < 4; reg++) {
                    int m = grow0 + reg;
                    int b = m >> 12, tt2 = m & 4095;
                    dst[(((size_t)(b * NH + hh)) * SEQ + tt2) * HS + d] = acc[fm][fn][reg];
                }
            }
        }
    }
}

// ---------------- landmarks ----------------
__global__ __launch_bounds__(256) void landmark_kernel(const float* __restrict__ q,
                                                       const float* __restrict__ k,
                                                       float* __restrict__ ql,
                                                       float* __restrict__ kl)
{
    int idx = blockIdx.x * 256 + threadIdx.x;
    int d = idx & 63, l = (idx >> 6) & 63, bh = idx >> 12;
    const float* qp = q + (((size_t)bh * SEQ) + l * 64) * HS + d;
    const float* kp = k + (((size_t)bh * SEQ) + l * 64) * HS + d;
    float sq = 0.f, sk = 0.f;
    for (int t = 0; t < 64; t++) { sq += qp[t * HS]; sk += kp[t * HS]; }
    ql[idx] = sq * (1.0f / 64.0f);
    kl[idx] = sk * (1.0f / 64.0f);
}

// ---------------- pinv (all-LDS Newton-Schulz) ----------------
__global__ __launch_bounds__(256) void pinv_kernel(const float* __restrict__ ql,
                                                   const float* __restrict__ kl,
                                                   float* __restrict__ Pbuf)
{
    int bh = blockIdx.x;
    __shared__ float Asm[64][65], V[64][65], KV[64][65], Tb[64][65], Ub[64][65];
    __shared__ float denom_s;
    int tid = threadIdx.x;
    int r = tid >> 2, c0 = (tid & 3) << 4;
    const float* qlp = ql + (size_t)bh * 4096;
    const float* klp = kl + (size_t)bh * 4096;

    for (int j = 0; j < 16; j++) {
        int cc = c0 + j; float acc = 0.f;
        for (int d = 0; d < 64; d++) acc += qlp[r * 64 + d] * klp[cc * 64 + d];
        Tb[r][cc] = acc;
    }
    __syncthreads();
    {
        float m = -1e30f;
        for (int j = 0; j < 64; j++) m = fmaxf(m, Tb[r][j]);
        float s = 0.f;
        for (int j = 0; j < 64; j++) s += expf(Tb[r][j] - m);
        float inv = 1.0f / s;
        for (int j = 0; j < 16; j++) {
            int cc = c0 + j;
            Asm[r][cc] = expf(Tb[r][cc] - m) * inv;
        }
    }
    __syncthreads();
    if (tid < 64) {
        float cs = 0.f;
        for (int i = 0; i < 64; i++) cs += Asm[i][tid];
        Ub[0][tid] = cs;
    }
    __syncthreads();
    if (tid == 0) {
        float mx = Ub[0][0];
        for (int j = 1; j < 64; j++) mx = fmaxf(mx, Ub[0][j]);
        denom_s = mx;
    }
    __syncthreads();
    for (int j = 0; j < 16; j++) { int cc = c0 + j; V[r][cc] = Asm[cc][r] / denom_s; }
    __syncthreads();

    float facc[16];
    for (int it = 0; it < 6; it++) {
        for (int j = 0; j < 16; j++) facc[j] = 0.f;
        for (int kx = 0; kx < 64; kx++) {
            float a = Asm[r][kx];
            for (int j = 0; j < 16; j++) facc[j] += a * V[kx][c0 + j];
        }
        for (int j = 0; j < 16; j++) KV[r][c0 + j] = facc[j];
        __syncthreads();
        for (int j = 0; j < 16; j++) {
            int cc = c0 + j;
            Tb[r][cc] = (r == cc ? 7.0f : 0.0f) - KV[r][cc];
        }
        __syncthreads();
        for (int j = 0; j < 16; j++) facc[j] = 0.f;
        for (int kx = 0; kx < 64; kx++) {
            float a = KV[r][kx];
            for (int j = 0; j < 16; j++) facc[j] += a * Tb[kx][c0 + j];
        }
        for (int j = 0; j < 16; j++) Ub[r][c0 + j] = facc[j];
        __syncthreads();
        for (int j = 0; j < 16; j++) {
            int cc = c0 + j;
            Tb[r][cc] = (r == cc ? 15.0f : 0.0f) - Ub[r][cc];
        }
        __syncthreads();
        for (int j = 0; j < 16; j++) facc[j] = 0.f;
        for (int kx = 0; kx < 64; kx++) {
            float a = KV[r][kx];
            for (int j = 0; j < 16; j++) facc[j] += a * Tb[kx][c0 + j];
        }
        for (int j = 0; j < 16; j++) Ub[r][c0 + j] = facc[j];
        __syncthreads();
        for (int j = 0; j < 16; j++) {
            int cc = c0 + j;
            Tb[r][cc] = (r == cc ? 13.0f : 0.0f) - Ub[r][cc];
        }
        __syncthreads();
        for (int j = 0; j < 16; j++) facc[j] = 0.f;
        for (int kx = 0; kx < 64; kx++) {
            float a = V[r][kx];
            for (int j = 0; j < 16; j++) facc[j] += a * Tb[kx][c0 + j];
        }
        for (int j = 0; j < 16; j++) Ub[r][c0 + j] = facc[j];
        __syncthreads();
        for (int j = 0; j < 16; j++) V[r][c0 + j] = 0.25f * Ub[r][c0 + j];
        __syncthreads();
    }
    for (int j = 0; j < 16; j++)
        Pbuf[(size_t)bh * 4096 + r * 64 + c0 + j] = V[r][c0 + j];
}

// ---------------- N path phase 1: per (bh, 256-wide t-chunk) partials ----------------
#define NVP 68
__global__ __launch_bounds__(256) void nv_partial(const float* __restrict__ ql,
                                                  const float* __restrict__ k,
                                                  const float* __restrict__ v,
                                                  float* __restrict__ pm,
                                                  float* __restrict__ ps,
                                                  float* __restrict__ pacc)
{
    int bh = blockIdx.y;
    int c0 = blockIdx.x;
    int tid = threadIdx.x;
    int rg = tid >> 4, tg = tid & 15;
    __shared__ float qlT[64][NVP];
    __shared__ float kT[64][NVP];
    __shared__ float vch[64][NVP];
    __shared__ float pch[64][NVP];

    {
        const float* qp = ql + (size_t)bh * 4096;
        for (int i = tid; i < 4096; i += 256) {
            int l = i >> 6, d = i & 63;
            qlT[d][l] = qp[i];
        }
    }

    float m_r[4], s_r[4];
    float acc[4][4];
    #pragma unroll
    for (int i = 0; i < 4; i++) {
        m_r[i] = -1e30f; s_r[i] = 0.f;
        #pragma unroll
        for (int j = 0; j < 4; j++) acc[i][j] = 0.f;
    }

    for (int sc = 0; sc < 4; sc++) {
        __syncthreads();
        const float* kp = k + ((size_t)bh * SEQ + c0 * 256 + sc * 64) * HS;
        const float* vp = v + ((size_t)bh * SEQ + c0 * 256 + sc * 64) * HS;
        for (int i = tid; i < 4096; i += 256) {
            int tt = i >> 6, d = i & 63;
            kT[d][tt]  = kp[i];
            vch[tt][d] = vp[i];
        }
        __syncthreads();

        float s[4][4] = {};
        #pragma unroll 4
        for (int dd = 0; dd < 64; dd++) {
            f32x4 a = *(const f32x4*)&qlT[dd][rg * 4];
            f32x4 b = *(const f32x4*)&kT[dd][tg * 4];
            #pragma unroll
            for (int i = 0; i < 4; i++)
                #pragma unroll
                for (int j = 0; j < 4; j++) s[i][j] += a[i] * b[j];
        }

        #pragma unroll
        for (int i = 0; i < 4; i++) {
            float tmax = fmaxf(fmaxf(s[i][0], s[i][1]), fmaxf(s[i][2], s[i][3]));
            #pragma unroll
            for (int off = 1; off < 16; off <<= 1)
                tmax = fmaxf(tmax, __shfl_xor(tmax, off, 64));
            float mnew = fmaxf(m_r[i], tmax);
            float alpha = expf(m_r[i] - mnew);
            m_r[i] = mnew;
            float psum = 0.f;
            #pragma unroll
            for (int j = 0; j < 4; j++) {
                float p = expf(s[i][j] - mnew);
                s[i][j] = p;
                psum += p;
            }
            #pragma unroll
            for (int off = 1; off < 16; off <<= 1)
                psum += __shfl_xor(psum, off, 64);
            s_r[i] = s_r[i] * alpha + psum;
            *(f32x4*)&pch[rg * 4 + i][tg * 4] = *(f32x4*)&s[i][0];
            #pragma unroll
            for (int j = 0; j < 4; j++) acc[i][j] *= alpha;
        }
        __syncthreads();

        #pragma unroll 2
        for (int tt = 0; tt < 64; tt++) {
            f32x4 vv = *(const f32x4*)&vch[tt][tg * 4];
            float p0 = pch[rg * 4 + 0][tt];
            float p1 = pch[rg * 4 + 1][tt];
            float p2 = pch[rg * 4 + 2][tt];
            float p3 = pch[rg * 4 + 3][tt];
            #pragma unroll
            for (int j = 0; j < 4; j++) {
                acc[0][j] += p0 * vv[j];
                acc[1][j] += p1 * vv[j];
                acc[2][j] += p2 * vv[j];
                acc[3][j] += p3 * vv[j];
            }
        }
    }

    float* paccp = pacc + ((((size_t)bh * 16 + c0) * 64) + rg * 4) * 64 + tg * 4;
    #pragma unroll
    for (int i = 0; i < 4; i++)
        *(f32x4*)&paccp[(size_t)i * 64] = *(f32x4*)&acc[i][0];
    if (tg == 0) {
        #pragma unroll
        for (int i = 0; i < 4; i++) {
            pm[((size_t)bh * 16 + c0) * 64 + rg * 4 + i] = m_r[i];
            ps[((size_t)bh * 16 + c0) * 64 + rg * 4 + i] = s_r[i];
        }
    }
}

// ---------------- N path phase 2: combine 16 chunk partials ----------------
__global__ __launch_bounds__(256) void nv_combine(const float* __restrict__ pm,
                                                  const float* __restrict__ ps,
                                                  const float* __restrict__ pacc,
                                                  float* __restrict__ Nv)
{
    int bh = blockIdx.x;
    int tid = threadIdx.x;
    int l = tid >> 2, dq = tid & 3;
    float m16[16];
    float gm = -1e30f;
    #pragma unroll
    for (int c = 0; c < 16; c++) {
        m16[c] = pm[((size_t)bh * 16 + c) * 64 + l];
        gm = fmaxf(gm, m16[c]);
    }
    float gs = 0.f;
    float e16[16];
    #pragma unroll
    for (int c = 0; c < 16; c++) {
        float e = expf(m16[c] - gm);
        e16[c] = e;
        gs += ps[((size_t)bh * 16 + c) * 64 + l] * e;
    }
    f32x4 a[4] = {};
    for (int c = 0; c < 16; c++) {
        float e = e16[c];
        const float* pp = pacc + (((size_t)bh * 16 + c) * 64 + l) * 64 + dq * 16;
        #pragma unroll
        for (int i = 0; i < 4; i++) {
            f32x4 t = *(const f32x4*)&pp[4 * i];
            a[i] += e * t;
        }
    }
    float inv = 1.0f / gs;
    float* np = Nv + (size_t)bh * 4096 + l * 64 + dq * 16;
    #pragma unroll
    for (int i = 0; i < 4; i++) {
        f32x4 o = a[i] * inv;
        *(f32x4*)&np[4 * i] = o;
    }
}

// ---------------- PNv = P @ Nv ----------------
__global__ __launch_bounds__(256) void pnv_kernel(const float* __restrict__ P,
                                                  const float* __restrict__ Nv,
                                                  float* __restrict__ PNv)
{
    int bh = blockIdx.x, tid = threadIdx.x;
    __shared__ float pb[64][65], nb[64][65];
    for (int i = tid; i < 4096; i += 256) {
        pb[i >> 6][i & 63] = P[(size_t)bh * 4096 + i];
        nb[i >> 6][i & 63] = Nv[(size_t)bh * 4096 + i];
    }
    __syncthreads();
    int r = tid >> 2, c0 = (tid & 3) << 4;
    for (int j = 0; j < 16; j++) {
        int cc = c0 + j; float acc = 0.f;
        for (int kx = 0; kx < 64; kx++) acc += pb[r][kx] * nb[kx][cc];
        PNv[(size_t)bh * 4096 + r * 64 + cc] = acc;
    }
}

// ---------------- y = softmax(q @ kl^T) @ PNv -> hi/lo bf16 (B,T,C) ----------------
__global__ __launch_bounds__(256) void y_kernel(const float* __restrict__ q,
                                                const float* __restrict__ kl,
                                                const float* __restrict__ PNv,
                                                bf16_t* __restrict__ yhi,
                                                bf16_t* __restrict__ ylo)
{
    int bh = blockIdx.y;
    int t0 = blockIdx.x * 64;
    int tid = threadIdx.x;
    __shared__ float qch[64][65], klb[64][65], pnv[64][65], srow[64][65];
    const float* qp = q + ((size_t)bh * SEQ + t0) * HS;
    for (int i = tid; i < 4096; i += 256) {
        qch[i >> 6][i & 63] = qp[i];
        klb[i >> 6][i & 63] = kl[(size_t)bh * 4096 + i];
        pnv[i >> 6][i & 63] = PNv[(size_t)bh * 4096 + i];
    }
    __syncthreads();
    int t = tid >> 2, l0 = (tid & 3) << 4;
    for (int j = 0; j < 16; j++) {
        int l = l0 + j; float acc = 0.f;
        for (int d = 0; d < 64; d++) acc += qch[t][d] * klb[l][d];
        srow[t][l] = acc;
    }
    __syncthreads();
    float m = -1e30f;
    for (int l = 0; l < 64; l++) m = fmaxf(m, srow[t][l]);
    float s = 0.f;
    for (int l = 0; l < 64; l++) s += expf(srow[t][l] - m);
    float inv = 1.0f / s;
    int d0 = (tid & 3) << 4;
    float acc[16] = {};
    for (int l = 0; l < 64; l++) {
        float w = expf(srow[t][l] - m) * inv;
        for (int j = 0; j < 16; j++) acc[j] += w * pnv[l][d0 + j];
    }
    int b = bh >> 4, h = bh & 15;
    size_t o = ((size_t)(b * SEQ) + t0 + t) * CDIM + h * HS + d0;
    for (int j = 0; j < 16; j++) {
        float v = acc[j];
        bf16_t hh = (bf16_t)v;
        yhi[o + j] = hh;
        ylo[o + j] = (bf16_t)(v - (float)hh);
    }
}

// ---------------- launch ----------------
extern "C" void kernel_launch(void* const* d_in, const int* in_sizes, int n_in,
                              void* d_out, int out_size, void* d_ws, size_t ws_size,
                              hipStream_t stream)
{
    const float* x  = (const float*)d_in[0];
    const float* Wa = (const float*)d_in[1];
    const float* Wp = (const float*)d_in[2];
    float* out = (float*)d_out;
    float* W = (float*)d_ws;

    const size_t off_q    = 0;
    const size_t off_k    = 16777216;
    const size_t off_v    = 33554432;
    const size_t off_ql   = 50331648;
    const size_t off_kl   = off_ql + 262144;
    const size_t off_P    = off_kl + 262144;
    const size_t off_Nv   = off_P  + 262144;
    const size_t off_PNv  = off_Nv + 262144;
    const size_t off_WatH = off_PNv + 262144;
    const size_t off_WatL = off_WatH + 1572864;
    const size_t off_WptH = off_WatL + 1572864;
    const size_t off_WptL = off_WptH + 524288;
    const size_t off_pm   = off_WptL + 524288;
    const size_t off_ps   = off_pm + 65536;
    const size_t off_pacc = off_ps + 65536;
    const size_t need = (off_pacc + 4194304) * sizeof(float);
    if (ws_size < need) {
        fprintf(stderr, "[nystrom] ws too small: have %zu need %zu\n", ws_size, need);
        return;
    }

    float* q    = W + off_q;
    float* k    = W + off_k;
    float* v    = W + off_v;
    float* ql   = W + off_ql;
    float* kl   = W + off_kl;
    float* P    = W + off_P;
    float* Nv   = W + off_Nv;
    float* PNv  = W + off_PNv;
    bf16_t* WatH = (bf16_t*)(W + off_WatH);
    bf16_t* WatL = (bf16_t*)(W + off_WatL);
    bf16_t* WptH = (bf16_t*)(W + off_WptH);
    bf16_t* WptL = (bf16_t*)(W + off_WptL);
    float* pm   = W + off_pm;
    float* ps   = W + off_ps;
    float* pacc = W + off_pacc;
    bf16_t* yhi = (bf16_t*)(W + off_k);       // alias k (dead after nv_partial)
    bf16_t* ylo = yhi + (size_t)MROWS * CDIM;
    // x split lives in d_out (dead as scratch until final proj GEMM writes it):
    // xhi+xlo = 2 * 16384*1024*2B = 64MB = out_size exactly.
    bf16_t* xhi = (bf16_t*)d_out;
    bf16_t* xlo = xhi + (size_t)MROWS * KDIM;

    transpose_split<<<dim3(N3 / 64, KDIM / 64), 256, 0, stream>>>(Wa, WatH, WatL, KDIM, N3);
    transpose_split<<<dim3(CDIM / 64, KDIM / 64), 256, 0, stream>>>(Wp, WptH, WptL, KDIM, CDIM);
    split_x<<<(MROWS * KDIM) / (256 * 8), 256, 0, stream>>>(x, xhi, xlo);
    gemm8<<<dim3(N3 / 256, MROWS / 256), 512, 0, stream>>>(xhi, xlo, WatH, WatL,
                                                           nullptr, q, k, v, N3, 1);
    landmark_kernel<<<262144 / 256, 256, 0, stream>>>(q, k, ql, kl);
    pinv_kernel<<<64, 256, 0, stream>>>(ql, kl, P);
    nv_partial<<<dim3(16, 64), 256, 0, stream>>>(ql, k, v, pm, ps, pacc);
    nv_combine<<<64, 256, 0, stream>>>(pm, ps, pacc, Nv);
    pnv_kernel<<<64, 256, 0, stream>>>(P, Nv, PNv);
    y_kernel<<<dim3(64, 64), 256, 0, stream>>>(q, kl, PNv, yhi, ylo);
    gemm8<<<dim3(CDIM / 256, MROWS / 256), 512, 0, stream>>>(yhi, ylo, WptH, WptL,
                                                             out, nullptr, nullptr, nullptr, CDIM, 0);
}

// Round 3
// 765.057 us; speedup vs baseline: 1.4955x; 1.4257x over previous
//
#include <hip/hip_runtime.h>
#include <hip/hip_bf16.h>
#include <cstdio>
#include <cstdint>

#define BATCH 4
#define SEQ   4096
#define CDIM  1024
#define NH    16
#define HS    64
#define NL    64
#define MROWS 16384
#define N3    3072
#define KDIM  1024
#define KT_N  48   // K' = 3*1024 / 64

typedef __bf16 bf16_t;
typedef bf16_t bf16x8 __attribute__((ext_vector_type(8)));
typedef bf16_t bf16x4 __attribute__((ext_vector_type(4)));
typedef float  f32x4  __attribute__((ext_vector_type(4)));

__device__ __forceinline__ void gld_lds16(const void* g, void* l)
{
    __builtin_amdgcn_global_load_lds((__attribute__((address_space(1))) void*)(void*)g,
                                     (__attribute__((address_space(3))) void*)l,
                                     16, 0, 0);
}

// ---------- W transpose + hi/lo bf16 split: dst[n][k] = split(src[k][n]) ----------
__global__ __launch_bounds__(256) void transpose_split(const float* __restrict__ src,
                                                       bf16_t* __restrict__ dhi,
                                                       bf16_t* __restrict__ dlo,
                                                       int K, int N)
{
    __shared__ float tile[64][65];
    int n0 = blockIdx.x * 64, k0 = blockIdx.y * 64;
    for (int idx = threadIdx.x; idx < 4096; idx += 256) {
        int rk = idx >> 6, cn = idx & 63;
        tile[rk][cn] = src[(size_t)(k0 + rk) * N + n0 + cn];
    }
    __syncthreads();
    for (int idx = threadIdx.x; idx < 4096; idx += 256) {
        int rn = idx >> 6, ck = idx & 63;
        float v = tile[ck][rn];
        bf16_t hh = (bf16_t)v;
        size_t o = (size_t)(n0 + rn) * K + k0 + ck;
        dhi[o] = hh;
        dlo[o] = (bf16_t)(v - (float)hh);
    }
}

// ---------- x (fp32) -> hi/lo bf16 split, vectorized ----------
__global__ __launch_bounds__(256) void split_x(const float* __restrict__ src,
                                               bf16_t* __restrict__ dhi,
                                               bf16_t* __restrict__ dlo)
{
    size_t i = ((size_t)blockIdx.x * 256 + threadIdx.x) * 8;
    f32x4 a = *(const f32x4*)(src + i);
    f32x4 b = *(const f32x4*)(src + i + 4);
    bf16x8 h, l;
    #pragma unroll
    for (int j = 0; j < 4; j++) {
        bf16_t hh = (bf16_t)a[j]; h[j] = hh; l[j] = (bf16_t)(a[j] - (float)hh);
    }
    #pragma unroll
    for (int j = 0; j < 4; j++) {
        bf16_t hh = (bf16_t)b[j]; h[4 + j] = hh; l[4 + j] = (bf16_t)(b[j] - (float)hh);
    }
    *(bf16x8*)(dhi + i) = h;
    *(bf16x8*)(dlo + i) = l;
}

// ---------- 256x256 8-phase MFMA GEMM over K'=3072 (split-bf16 as 3 K-passes) ----------
// (unchanged from round 2: T2 both-sides swizzle, counted vmcnt, verified)
__global__ __launch_bounds__(512, 2) void gemm8(const bf16_t* __restrict__ Ahi,
                                                const bf16_t* __restrict__ Alo,
                                                const bf16_t* __restrict__ Bhi,
                                                const bf16_t* __restrict__ Blo,
                                                float* __restrict__ C0,
                                                float* __restrict__ Cq,
                                                float* __restrict__ Ck,
                                                float* __restrict__ Cv,
                                                int N, int mode)
{
    __shared__ __align__(16) bf16_t lds[2][2][2][256][32];   // 128 KiB

    int tid  = threadIdx.x;
    int lane = tid & 63, wv = tid >> 6;
    int wr = wv >> 2, wc = wv & 3;          // 2M x 4N wave grid
    int lm = lane & 15, lk = lane >> 4;

    int nbx  = N >> 8;
    int flat = blockIdx.y * nbx + blockIdx.x;
    int nwg  = nbx * (int)gridDim.y;
    int cpx  = nwg >> 3;
    int swzb = (flat & 7) * cpx + (flat >> 3);
    int m0 = (swzb / nbx) << 8;
    int n0 = (swzb % nbx) << 8;

    int wrow0 = wv << 5;
    int wrow1 = wrow0 + 16;
    int srow  = lane >> 2;
    int ssc8  = (((lane & 3) ^ ((lane >> 3) & 3)) << 3);
    size_t ga0 = (size_t)(m0 + wrow0 + srow) * KDIM + ssc8;
    size_t ga1 = (size_t)(m0 + wrow1 + srow) * KDIM + ssc8;
    size_t gb0 = (size_t)(n0 + wrow0 + srow) * KDIM + ssc8;
    size_t gb1 = (size_t)(n0 + wrow1 + srow) * KDIM + ssc8;

    auto stageA = [&](int tt, int kh) {
        const bf16_t* s = (tt < 32) ? Ahi : Alo;
        int kcol = ((tt & 15) << 6) + (kh << 5);
        int buf  = tt & 1;
        gld_lds16(s + ga0 + kcol, &lds[buf][0][kh][wrow0][0]);
        gld_lds16(s + ga1 + kcol, &lds[buf][0][kh][wrow1][0]);
    };
    auto stageB = [&](int tt, int kh) {
        const bf16_t* s = (tt < 16 || tt >= 32) ? Bhi : Blo;
        int kcol = ((tt & 15) << 6) + (kh << 5);
        int buf  = tt & 1;
        gld_lds16(s + gb0 + kcol, &lds[buf][1][kh][wrow0][0]);
        gld_lds16(s + gb1 + kcol, &lds[buf][1][kh][wrow1][0]);
    };

    f32x4 acc[8][4] = {};

    stageA(0, 0); stageB(0, 0);
    stageA(0, 1); stageB(0, 1);
    stageA(1, 0); stageB(1, 0);
    asm volatile("s_waitcnt vmcnt(8)" ::: "memory");
    __builtin_amdgcn_s_barrier();

    int arow = wr * 128 + lm;
    int brow = wc * 64 + lm;
    int kswz = 8 * (lk ^ ((lm >> 1) & 3));   // T2 read-side swizzled column

    for (int t = 0; t < KT_N; ++t) {
        int buf  = t & 1;
        bf16x8 afr[4], bfr[4];

        // ---- Phase 0 ----
        #pragma unroll
        for (int i = 0; i < 4; i++)
            afr[i] = *(const bf16x8*)&lds[buf][0][0][arow + i * 16][kswz];
        #pragma unroll
        for (int j = 0; j < 4; j++)
            bfr[j] = *(const bf16x8*)&lds[buf][1][0][brow + j * 16][kswz];
        if (t + 1 < KT_N) stageA(t + 1, 1);
        __builtin_amdgcn_s_barrier();
        asm volatile("s_waitcnt lgkmcnt(0)" ::: "memory");
        __builtin_amdgcn_sched_barrier(0);
        __builtin_amdgcn_s_setprio(1);
        #pragma unroll
        for (int i = 0; i < 4; i++)
            #pragma unroll
            for (int j = 0; j < 4; j++)
                acc[i][j] = __builtin_amdgcn_mfma_f32_16x16x32_bf16(afr[i], bfr[j], acc[i][j], 0, 0, 0);
        __builtin_amdgcn_s_setprio(0);
        __builtin_amdgcn_sched_barrier(0);
        __builtin_amdgcn_s_barrier();

        // ---- Phase 1 ----
        #pragma unroll
        for (int i = 0; i < 4; i++)
            afr[i] = *(const bf16x8*)&lds[buf][0][0][arow + (i + 4) * 16][kswz];
        if (t + 1 < KT_N) stageB(t + 1, 1);
        __builtin_amdgcn_s_barrier();
        asm volatile("s_waitcnt lgkmcnt(0)" ::: "memory");
        __builtin_amdgcn_sched_barrier(0);
        __builtin_amdgcn_s_setprio(1);
        #pragma unroll
        for (int i = 0; i < 4; i++)
            #pragma unroll
            for (int j = 0; j < 4; j++)
                acc[i + 4][j] = __builtin_amdgcn_mfma_f32_16x16x32_bf16(afr[i], bfr[j], acc[i + 4][j], 0, 0, 0);
        __builtin_amdgcn_s_setprio(0);
        __builtin_amdgcn_sched_barrier(0);
        if (t + 1 < KT_N) { asm volatile("s_waitcnt vmcnt(8)" ::: "memory"); }
        else              { asm volatile("s_waitcnt vmcnt(0)" ::: "memory"); }
        __builtin_amdgcn_s_barrier();

        // ---- Phase 2 ----
        #pragma unroll
        for (int i = 0; i < 4; i++)
            afr[i] = *(const bf16x8*)&lds[buf][0][1][arow + i * 16][kswz];
        #pragma unroll
        for (int j = 0; j < 4; j++)
            bfr[j] = *(const bf16x8*)&lds[buf][1][1][brow + j * 16][kswz];
        if (t + 2 < KT_N) stageA(t + 2, 0);
        __builtin_amdgcn_s_barrier();
        asm volatile("s_waitcnt lgkmcnt(0)" ::: "memory");
        __builtin_amdgcn_sched_barrier(0);
        __builtin_amdgcn_s_setprio(1);
        #pragma unroll
        for (int i = 0; i < 4; i++)
            #pragma unroll
            for (int j = 0; j < 4; j++)
                acc[i][j] = __builtin_amdgcn_mfma_f32_16x16x32_bf16(afr[i], bfr[j], acc[i][j], 0, 0, 0);
        __builtin_amdgcn_s_setprio(0);
        __builtin_amdgcn_sched_barrier(0);
        __builtin_amdgcn_s_barrier();

        // ---- Phase 3 ----
        #pragma unroll
        for (int i = 0; i < 4; i++)
            afr[i] = *(const bf16x8*)&lds[buf][0][1][arow + (i + 4) * 16][kswz];
        if (t + 2 < KT_N) stageB(t + 2, 0);
        __builtin_amdgcn_s_barrier();
        asm volatile("s_waitcnt lgkmcnt(0)" ::: "memory");
        __builtin_amdgcn_sched_barrier(0);
        __builtin_amdgcn_s_setprio(1);
        #pragma unroll
        for (int i = 0; i < 4; i++)
            #pragma unroll
            for (int j = 0; j < 4; j++)
                acc[i + 4][j] = __builtin_amdgcn_mfma_f32_16x16x32_bf16(afr[i], bfr[j], acc[i + 4][j], 0, 0, 0);
        __builtin_amdgcn_s_setprio(0);
        __builtin_amdgcn_sched_barrier(0);
        if (t + 2 < KT_N)      { asm volatile("s_waitcnt vmcnt(8)" ::: "memory"); }
        else if (t + 1 < KT_N) { asm volatile("s_waitcnt vmcnt(4)" ::: "memory"); }
        __builtin_amdgcn_s_barrier();
    }

    if (mode == 0) {
        #pragma unroll
        for (int fm = 0; fm < 8; fm++) {
            int grow0 = m0 + wr * 128 + fm * 16 + lk * 4;
            #pragma unroll
            for (int fn = 0; fn < 4; fn++) {
                int gcol = n0 + wc * 64 + fn * 16 + lm;
                #pragma unroll
                for (int reg = 0; reg < 4; reg++)
                    C0[(size_t)(grow0 + reg) * N + gcol] = acc[fm][fn][reg];
            }
        }
    } else {
        #pragma unroll
        for (int fm = 0; fm < 8; fm++) {
            int grow0 = m0 + wr * 128 + fm * 16 + lk * 4;
            #pragma unroll
            for (int fn = 0; fn < 4; fn++) {
                int n = n0 + wc * 64 + fn * 16 + lm;
                float* dst; int nn;
                if (n < 1024)      { dst = Cq; nn = n; }
                else if (n < 2048) { dst = Ck; nn = n - 1024; }
                else               { dst = Cv; nn = n - 2048; }
                int hh = nn >> 6, d = nn & 63;
                #pragma unroll
                for (int reg = 0; reg < 4; reg++) {
                    int m = grow0 + reg;
                    int b = m >> 12, tt2 = m & 4095;
                    dst[(((size_t)(b * NH + hh)) * SEQ + tt2) * HS + d] = acc[fm][fn][reg];
                }
            }
        }
    }
}

// ---------------- landmarks ----------------
__global__ __launch_bounds__(256) void landmark_kernel(const float* __restrict__ q,
                                                       const float* __restrict__ k,
                                                       float* __restrict__ ql,
                                                       float* __restrict__ kl)
{
    int idx = blockIdx.x * 256 + threadIdx.x;
    int d = idx & 63, l = (idx >> 6) & 63, bh = idx >> 12;
    const float* qp = q + (((size_t)bh * SEQ) + l * 64) * HS + d;
    const float* kp = k + (((size_t)bh * SEQ) + l * 64) * HS + d;
    float sq = 0.f, sk = 0.f;
    for (int t = 0; t < 64; t++) { sq += qp[t * HS]; sk += kp[t * HS]; }
    ql[idx] = sq * (1.0f / 64.0f);
    kl[idx] = sk * (1.0f / 64.0f);
}

// ---------------- pinv (all-LDS Newton-Schulz, 4x4 register-tiled) ----------------
// Left operands kept transposed (AsmT/KVT/VT) so each k-step of every 64^3
// matmul is 2x aligned f32x4 LDS reads + 16 FMA (was 17 scalar reads).
#define PPAD 68
__global__ __launch_bounds__(256) void pinv_kernel(const float* __restrict__ ql,
                                                   const float* __restrict__ kl,
                                                   float* __restrict__ Pbuf)
{
    int bh = blockIdx.x;
    __shared__ float AsmM[64][PPAD], AsmT[64][PPAD], V[64][PPAD], VT[64][PPAD],
                     KV[64][PPAD], KVT[64][PPAD], Tb[64][PPAD];
    __shared__ float colsum[64];
    __shared__ float denom_s;
    int tid = threadIdx.x;
    int ri = tid >> 4, cj = tid & 15;
    int r0 = ri * 4, c0 = cj * 4;

    // stage ql,kl transposed into KV/KVT (dead until first matmul writes them)
    {
        const float* qp = ql + (size_t)bh * 4096;
        const float* kp = kl + (size_t)bh * 4096;
        for (int i = tid; i < 4096; i += 256) {
            int l = i >> 6, d = i & 63;
            KV[d][l]  = qp[i];   // qlT
            KVT[d][l] = kp[i];   // klT
        }
    }
    __syncthreads();

    // scores S = ql @ kl^T (4x4 tile per thread)
    float c[4][4] = {};
    for (int d = 0; d < 64; d++) {
        f32x4 a = *(const f32x4*)&KV[d][r0];
        f32x4 b = *(const f32x4*)&KVT[d][c0];
        #pragma unroll
        for (int i = 0; i < 4; i++)
            #pragma unroll
            for (int j = 0; j < 4; j++) c[i][j] += a[i] * b[j];
    }
    // rowwise softmax (rows split across the 16-lane cj group)
    #pragma unroll
    for (int i = 0; i < 4; i++) {
        float tmax = fmaxf(fmaxf(c[i][0], c[i][1]), fmaxf(c[i][2], c[i][3]));
        #pragma unroll
        for (int off = 1; off < 16; off <<= 1)
            tmax = fmaxf(tmax, __shfl_xor(tmax, off, 64));
        float psum = 0.f;
        #pragma unroll
        for (int j = 0; j < 4; j++) {
            float p = expf(c[i][j] - tmax);
            c[i][j] = p; psum += p;
        }
        #pragma unroll
        for (int off = 1; off < 16; off <<= 1)
            psum += __shfl_xor(psum, off, 64);
        float inv = 1.0f / psum;
        #pragma unroll
        for (int j = 0; j < 4; j++) c[i][j] *= inv;
    }
    __syncthreads();   // done reading qlT/klT (KV/KVT about to be logical Asm store targets later)
    #pragma unroll
    for (int i = 0; i < 4; i++) {
        *(f32x4*)&AsmM[r0 + i][c0] = *(f32x4*)&c[i][0];
        #pragma unroll
        for (int j = 0; j < 4; j++) AsmT[c0 + j][r0 + i] = c[i][j];
    }
    __syncthreads();

    // denom = max over columns of column-sums; colsum[c] = sum of AsmT row c
    if (tid < 64) {
        float cs = 0.f;
        for (int x = 0; x < 64; x += 4) {
            f32x4 t = *(const f32x4*)&AsmT[tid][x];
            cs += t[0] + t[1] + t[2] + t[3];
        }
        colsum[tid] = cs;
    }
    __syncthreads();
    if (tid == 0) {
        float mx = colsum[0];
        for (int j = 1; j < 64; j++) mx = fmaxf(mx, colsum[j]);
        denom_s = mx;
    }
    __syncthreads();
    {
        float dinv = 1.0f / denom_s;
        #pragma unroll
        for (int i = 0; i < 4; i++) {
            f32x4 t = *(const f32x4*)&AsmT[r0 + i][c0];
            f32x4 o = t * dinv;
            *(f32x4*)&V[r0 + i][c0] = o;
            #pragma unroll
            for (int j = 0; j < 4; j++) VT[c0 + j][r0 + i] = o[j];
        }
    }
    __syncthreads();

    float u[4][4];
    for (int it = 0; it < 6; it++) {
        // M1: KV = Asm @ V
        #pragma unroll
        for (int i = 0; i < 4; i++)
            #pragma unroll
            for (int j = 0; j < 4; j++) c[i][j] = 0.f;
        for (int kx = 0; kx < 64; kx++) {
            f32x4 a = *(const f32x4*)&AsmT[kx][r0];
            f32x4 b = *(const f32x4*)&V[kx][c0];
            #pragma unroll
            for (int i = 0; i < 4; i++)
                #pragma unroll
                for (int j = 0; j < 4; j++) c[i][j] += a[i] * b[j];
        }
        __syncthreads();   // everyone done reading V (and old KV/KVT not in use)
        #pragma unroll
        for (int i = 0; i < 4; i++) {
            *(f32x4*)&KV[r0 + i][c0] = *(f32x4*)&c[i][0];
            #pragma unroll
            for (int j = 0; j < 4; j++) {
                KVT[c0 + j][r0 + i] = c[i][j];
                Tb[r0 + i][c0 + j] = ((r0 + i) == (c0 + j) ? 7.0f : 0.0f) - c[i][j];
            }
        }
        __syncthreads();
        // M2: U = KV @ T1
        #pragma unroll
        for (int i = 0; i < 4; i++)
            #pragma unroll
            for (int j = 0; j < 4; j++) u[i][j] = 0.f;
        for (int kx = 0; kx < 64; kx++) {
            f32x4 a = *(const f32x4*)&KVT[kx][r0];
            f32x4 b = *(const f32x4*)&Tb[kx][c0];
            #pragma unroll
            for (int i = 0; i < 4; i++)
                #pragma unroll
                for (int j = 0; j < 4; j++) u[i][j] += a[i] * b[j];
        }
        __syncthreads();
        #pragma unroll
        for (int i = 0; i < 4; i++)
            #pragma unroll
            for (int j = 0; j < 4; j++)
                Tb[r0 + i][c0 + j] = ((r0 + i) == (c0 + j) ? 15.0f : 0.0f) - u[i][j];
        __syncthreads();
        // M3: U2 = KV @ T2
        #pragma unroll
        for (int i = 0; i < 4; i++)
            #pragma unroll
            for (int j = 0; j < 4; j++) u[i][j] = 0.f;
        for (int kx = 0; kx < 64; kx++) {
            f32x4 a = *(const f32x4*)&KVT[kx][r0];
            f32x4 b = *(const f32x4*)&Tb[kx][c0];
            #pragma unroll
            for (int i = 0; i < 4; i++)
                #pragma unroll
                for (int j = 0; j < 4; j++) u[i][j] += a[i] * b[j];
        }
        __syncthreads();
        #pragma unroll
        for (int i = 0; i < 4; i++)
            #pragma unroll
            for (int j = 0; j < 4; j++)
                Tb[r0 + i][c0 + j] = ((r0 + i) == (c0 + j) ? 13.0f : 0.0f) - u[i][j];
        __syncthreads();
        // M4: Vn = 0.25 * V @ T3
        #pragma unroll
        for (int i = 0; i < 4; i++)
            #pragma unroll
            for (int j = 0; j < 4; j++) c[i][j] = 0.f;
        for (int kx = 0; kx < 64; kx++) {
            f32x4 a = *(const f32x4*)&VT[kx][r0];
            f32x4 b = *(const f32x4*)&Tb[kx][c0];
            #pragma unroll
            for (int i = 0; i < 4; i++)
                #pragma unroll
                for (int j = 0; j < 4; j++) c[i][j] += a[i] * b[j];
        }
        __syncthreads();   // everyone done reading VT
        #pragma unroll
        for (int i = 0; i < 4; i++) {
            f32x4 o;
            #pragma unroll
            for (int j = 0; j < 4; j++) o[j] = 0.25f * c[i][j];
            *(f32x4*)&V[r0 + i][c0] = o;
            #pragma unroll
            for (int j = 0; j < 4; j++) VT[c0 + j][r0 + i] = o[j];
        }
        __syncthreads();
    }
    #pragma unroll
    for (int i = 0; i < 4; i++)
        *(f32x4*)&Pbuf[(size_t)bh * 4096 + (r0 + i) * 64 + c0] = *(const f32x4*)&V[r0 + i][c0];
}

// ---------------- N path phase 1: per (bh, 256-wide t-chunk) partials ----------------
#define NVP 68
__global__ __launch_bounds__(256) void nv_partial(const float* __restrict__ ql,
                                                  const float* __restrict__ k,
                                                  const float* __restrict__ v,
                                                  float* __restrict__ pm,
                                                  float* __restrict__ ps,
                                                  float* __restrict__ pacc)
{
    int bh = blockIdx.y;
    int c0 = blockIdx.x;
    int tid = threadIdx.x;
    int rg = tid >> 4, tg = tid & 15;
    __shared__ float qlT[64][NVP];
    __shared__ float kT[64][NVP];
    __shared__ float vch[64][NVP];
    __shared__ float pchT[64][NVP];   // [t][l-row]: P transposed for f32x4 PV reads

    {
        const float* qp = ql + (size_t)bh * 4096;
        for (int i = tid; i < 4096; i += 256) {
            int l = i >> 6, d = i & 63;
            qlT[d][l] = qp[i];
        }
    }

    float m_r[4], s_r[4];
    float acc[4][4];
    #pragma unroll
    for (int i = 0; i < 4; i++) {
        m_r[i] = -1e30f; s_r[i] = 0.f;
        #pragma unroll
        for (int j = 0; j < 4; j++) acc[i][j] = 0.f;
    }

    for (int sc = 0; sc < 4; sc++) {
        __syncthreads();
        const float* kp = k + ((size_t)bh * SEQ + c0 * 256 + sc * 64) * HS;
        const float* vp = v + ((size_t)bh * SEQ + c0 * 256 + sc * 64) * HS;
        for (int i = tid; i < 4096; i += 256) {
            int tt = i >> 6, d = i & 63;
            kT[d][tt]  = kp[i];
            vch[tt][d] = vp[i];
        }
        __syncthreads();

        float s[4][4] = {};
        #pragma unroll 4
        for (int dd = 0; dd < 64; dd++) {
            f32x4 a = *(const f32x4*)&qlT[dd][rg * 4];
            f32x4 b = *(const f32x4*)&kT[dd][tg * 4];
            #pragma unroll
            for (int i = 0; i < 4; i++)
                #pragma unroll
                for (int j = 0; j < 4; j++) s[i][j] += a[i] * b[j];
        }

        #pragma unroll
        for (int i = 0; i < 4; i++) {
            float tmax = fmaxf(fmaxf(s[i][0], s[i][1]), fmaxf(s[i][2], s[i][3]));
            #pragma unroll
            for (int off = 1; off < 16; off <<= 1)
                tmax = fmaxf(tmax, __shfl_xor(tmax, off, 64));
            float mnew = fmaxf(m_r[i], tmax);
            float alpha = expf(m_r[i] - mnew);
            m_r[i] = mnew;
            float psum = 0.f;
            #pragma unroll
            for (int j = 0; j < 4; j++) {
                float p = expf(s[i][j] - mnew);
                s[i][j] = p;
                psum += p;
            }
            #pragma unroll
            for (int off = 1; off < 16; off <<= 1)
                psum += __shfl_xor(psum, off, 64);
            s_r[i] = s_r[i] * alpha + psum;
            #pragma unroll
            for (int j = 0; j < 4; j++) pchT[tg * 4 + j][rg * 4 + i] = s[i][j];
            #pragma unroll
            for (int j = 0; j < 4; j++) acc[i][j] *= alpha;
        }
        __syncthreads();

        // PV: acc[i][j] += sum_t P[row_i][t] * v[t][d_j]  (2x b128 per t)
        #pragma unroll 2
        for (int tt = 0; tt < 64; tt++) {
            f32x4 vv = *(const f32x4*)&vch[tt][tg * 4];
            f32x4 pr = *(const f32x4*)&pchT[tt][rg * 4];
            #pragma unroll
            for (int i = 0; i < 4; i++)
                #pragma unroll
                for (int j = 0; j < 4; j++)
                    acc[i][j] += pr[i] * vv[j];
        }
    }

    float* paccp = pacc + ((((size_t)bh * 16 + c0) * 64) + rg * 4) * 64 + tg * 4;
    #pragma unroll
    for (int i = 0; i < 4; i++)
        *(f32x4*)&paccp[(size_t)i * 64] = *(f32x4*)&acc[i][0];
    if (tg == 0) {
        #pragma unroll
        for (int i = 0; i < 4; i++) {
            pm[((size_t)bh * 16 + c0) * 64 + rg * 4 + i] = m_r[i];
            ps[((size_t)bh * 16 + c0) * 64 + rg * 4 + i] = s_r[i];
        }
    }
}

// ---------------- N path phase 2: combine 16 chunk partials ----------------
__global__ __launch_bounds__(256) void nv_combine(const float* __restrict__ pm,
                                                  const float* __restrict__ ps,
                                                  const float* __restrict__ pacc,
                                                  float* __restrict__ Nv)
{
    int bh = blockIdx.x;
    int tid = threadIdx.x;
    int l = tid >> 2, dq = tid & 3;
    float m16[16];
    float gm = -1e30f;
    #pragma unroll
    for (int c = 0; c < 16; c++) {
        m16[c] = pm[((size_t)bh * 16 + c) * 64 + l];
        gm = fmaxf(gm, m16[c]);
    }
    float gs = 0.f;
    float e16[16];
    #pragma unroll
    for (int c = 0; c < 16; c++) {
        float e = expf(m16[c] - gm);
        e16[c] = e;
        gs += ps[((size_t)bh * 16 + c) * 64 + l] * e;
    }
    f32x4 a[4] = {};
    for (int c = 0; c < 16; c++) {
        float e = e16[c];
        const float* pp = pacc + (((size_t)bh * 16 + c) * 64 + l) * 64 + dq * 16;
        #pragma unroll
        for (int i = 0; i < 4; i++) {
            f32x4 t = *(const f32x4*)&pp[4 * i];
            a[i] += e * t;
        }
    }
    float inv = 1.0f / gs;
    float* np = Nv + (size_t)bh * 4096 + l * 64 + dq * 16;
    #pragma unroll
    for (int i = 0; i < 4; i++) {
        f32x4 o = a[i] * inv;
        *(f32x4*)&np[4 * i] = o;
    }
}

// ---------------- PNv = P @ Nv ----------------
__global__ __launch_bounds__(256) void pnv_kernel(const float* __restrict__ P,
                                                  const float* __restrict__ Nv,
                                                  float* __restrict__ PNv)
{
    int bh = blockIdx.x, tid = threadIdx.x;
    __shared__ float pb[64][65], nb[64][65];
    for (int i = tid; i < 4096; i += 256) {
        pb[i >> 6][i & 63] = P[(size_t)bh * 4096 + i];
        nb[i >> 6][i & 63] = Nv[(size_t)bh * 4096 + i];
    }
    __syncthreads();
    int r = tid >> 2, c0 = (tid & 3) << 4;
    for (int j = 0; j < 16; j++) {
        int cc = c0 + j; float acc = 0.f;
        for (int kx = 0; kx < 64; kx++) acc += pb[r][kx] * nb[kx][cc];
        PNv[(size_t)bh * 4096 + r * 64 + cc] = acc;
    }
}

// ---------------- y = softmax(q @ kl^T) @ PNv -> hi/lo bf16 (B,T,C) ----------------
// 4x4 register-tiled, transposed staging, shfl row-softmax, transposed P.
__global__ __launch_bounds__(256) void y_kernel(const float* __restrict__ q,
                                                const float* __restrict__ kl,
                                                const float* __restrict__ PNv,
                                                bf16_t* __restrict__ yhi,
                                                bf16_t* __restrict__ ylo)
{
    int bh = blockIdx.y;
    int t0 = blockIdx.x * 64;
    int tid = threadIdx.x;
    __shared__ float qT[64][NVP], klT[64][NVP], pnv[64][NVP], pT[64][NVP];
    const float* qp = q + ((size_t)bh * SEQ + t0) * HS;
    const float* kp = kl + (size_t)bh * 4096;
    const float* pp = PNv + (size_t)bh * 4096;
    for (int i = tid; i < 4096; i += 256) {
        int r = i >> 6, d = i & 63;
        qT[d][r]  = qp[i];
        klT[d][r] = kp[i];
        pnv[r][d] = pp[i];
    }
    __syncthreads();

    int ti = tid >> 4, gj = tid & 15;
    int r0 = ti * 4, c0 = gj * 4;

    // scores S[4t][4l]
    float s[4][4] = {};
    for (int d = 0; d < 64; d++) {
        f32x4 a = *(const f32x4*)&qT[d][r0];
        f32x4 b = *(const f32x4*)&klT[d][c0];
        #pragma unroll
        for (int i = 0; i < 4; i++)
            #pragma unroll
            for (int j = 0; j < 4; j++) s[i][j] += a[i] * b[j];
    }
    // row softmax across 16-lane gj group
    #pragma unroll
    for (int i = 0; i < 4; i++) {
        float tmax = fmaxf(fmaxf(s[i][0], s[i][1]), fmaxf(s[i][2], s[i][3]));
        #pragma unroll
        for (int off = 1; off < 16; off <<= 1)
            tmax = fmaxf(tmax, __shfl_xor(tmax, off, 64));
        float psum = 0.f;
        #pragma unroll
        for (int j = 0; j < 4; j++) {
            float p = expf(s[i][j] - tmax);
            s[i][j] = p; psum += p;
        }
        #pragma unroll
        for (int off = 1; off < 16; off <<= 1)
            psum += __shfl_xor(psum, off, 64);
        float inv = 1.0f / psum;
        #pragma unroll
        for (int j = 0; j < 4; j++) s[i][j] *= inv;
    }
    #pragma unroll
    for (int i = 0; i < 4; i++)
        #pragma unroll
        for (int j = 0; j < 4; j++) pT[c0 + j][r0 + i] = s[i][j];
    __syncthreads();

    // PV: out[4t][4d], d-cols c0..
    float o[4][4] = {};
    for (int l = 0; l < 64; l++) {
        f32x4 a = *(const f32x4*)&pT[l][r0];
        f32x4 b = *(const f32x4*)&pnv[l][c0];
        #pragma unroll
        for (int i = 0; i < 4; i++)
            #pragma unroll
            for (int j = 0; j < 4; j++) o[i][j] += a[i] * b[j];
    }

    int b = bh >> 4, h = bh & 15;
    #pragma unroll
    for (int i = 0; i < 4; i++) {
        bf16x4 hv, lv;
        #pragma unroll
        for (int j = 0; j < 4; j++) {
            float v = o[i][j];
            bf16_t hh = (bf16_t)v;
            hv[j] = hh;
            lv[j] = (bf16_t)(v - (float)hh);
        }
        size_t oo = ((size_t)(b * SEQ) + t0 + r0 + i) * CDIM + h * HS + c0;
        *(bf16x4*)(yhi + oo) = hv;
        *(bf16x4*)(ylo + oo) = lv;
    }
}

// ---------------- launch ----------------
extern "C" void kernel_launch(void* const* d_in, const int* in_sizes, int n_in,
                              void* d_out, int out_size, void* d_ws, size_t ws_size,
                              hipStream_t stream)
{
    const float* x  = (const float*)d_in[0];
    const float* Wa = (const float*)d_in[1];
    const float* Wp = (const float*)d_in[2];
    float* out = (float*)d_out;
    float* W = (float*)d_ws;

    const size_t off_q    = 0;
    const size_t off_k    = 16777216;
    const size_t off_v    = 33554432;
    const size_t off_ql   = 50331648;
    const size_t off_kl   = off_ql + 262144;
    const size_t off_P    = off_kl + 262144;
    const size_t off_Nv   = off_P  + 262144;
    const size_t off_PNv  = off_Nv + 262144;
    const size_t off_WatH = off_PNv + 262144;
    const size_t off_WatL = off_WatH + 1572864;
    const size_t off_WptH = off_WatL + 1572864;
    const size_t off_WptL = off_WptH + 524288;
    const size_t off_pm   = off_WptL + 524288;
    const size_t off_ps   = off_pm + 65536;
    const size_t off_pacc = off_ps + 65536;
    const size_t need = (off_pacc + 4194304) * sizeof(float);
    if (ws_size < need) {
        fprintf(stderr, "[nystrom] ws too small: have %zu need %zu\n", ws_size, need);
        return;
    }

    float* q    = W + off_q;
    float* k    = W + off_k;
    float* v    = W + off_v;
    float* ql   = W + off_ql;
    float* kl   = W + off_kl;
    float* P    = W + off_P;
    float* Nv   = W + off_Nv;
    float* PNv  = W + off_PNv;
    bf16_t* WatH = (bf16_t*)(W + off_WatH);
    bf16_t* WatL = (bf16_t*)(W + off_WatL);
    bf16_t* WptH = (bf16_t*)(W + off_WptH);
    bf16_t* WptL = (bf16_t*)(W + off_WptL);
    float* pm   = W + off_pm;
    float* ps   = W + off_ps;
    float* pacc = W + off_pacc;
    bf16_t* yhi = (bf16_t*)(W + off_k);       // alias k (dead after nv_partial)
    bf16_t* ylo = yhi + (size_t)MROWS * CDIM;
    bf16_t* xhi = (bf16_t*)d_out;             // d_out scratch until final GEMM
    bf16_t* xlo = xhi + (size_t)MROWS * KDIM;

    transpose_split<<<dim3(N3 / 64, KDIM / 64), 256, 0, stream>>>(Wa, WatH, WatL, KDIM, N3);
    transpose_split<<<dim3(CDIM / 64, KDIM / 64), 256, 0, stream>>>(Wp, WptH, WptL, KDIM, CDIM);
    split_x<<<(MROWS * KDIM) / (256 * 8), 256, 0, stream>>>(x, xhi, xlo);
    gemm8<<<dim3(N3 / 256, MROWS / 256), 512, 0, stream>>>(xhi, xlo, WatH, WatL,
                                                           nullptr, q, k, v, N3, 1);
    landmark_kernel<<<262144 / 256, 256, 0, stream>>>(q, k, ql, kl);
    pinv_kernel<<<64, 256, 0, stream>>>(ql, kl, P);
    nv_partial<<<dim3(16, 64), 256, 0, stream>>>(ql, k, v, pm, ps, pacc);
    nv_combine<<<64, 256, 0, stream>>>(pm, ps, pacc, Nv);
    pnv_kernel<<<64, 256, 0, stream>>>(P, Nv, PNv);
    y_kernel<<<dim3(64, 64), 256, 0, stream>>>(q, kl, PNv, yhi, ylo);
    gemm8<<<dim3(CDIM / 256, MROWS / 256), 512, 0, stream>>>(yhi, ylo, WptH, WptL,
                                                             out, nullptr, nullptr, nullptr, CDIM, 0);
}

// Round 5
// 763.759 us; speedup vs baseline: 1.4980x; 1.0017x over previous
//
#include <hip/hip_runtime.h>
#include <hip/hip_bf16.h>
#include <cstdio>
#include <cstdint>

#define BATCH 4
#define SEQ   4096
#define CDIM  1024
#define NH    16
#define HS    64
#define NL    64
#define MROWS 16384
#define N3    3072
#define KDIM  1024
#define KT_N  48   // K' = 3*1024 / 64

typedef __bf16 bf16_t;
typedef bf16_t bf16x8 __attribute__((ext_vector_type(8)));
typedef bf16_t bf16x4 __attribute__((ext_vector_type(4)));
typedef float  f32x4  __attribute__((ext_vector_type(4)));

__device__ __forceinline__ void gld_lds16(const void* g, void* l)
{
    __builtin_amdgcn_global_load_lds((__attribute__((address_space(1))) void*)(void*)g,
                                     (__attribute__((address_space(3))) void*)l,
                                     16, 0, 0);
}

// ---------- W transpose + hi/lo bf16 split: dst[n][k] = split(src[k][n]) ----------
__global__ __launch_bounds__(256) void transpose_split(const float* __restrict__ src,
                                                       bf16_t* __restrict__ dhi,
                                                       bf16_t* __restrict__ dlo,
                                                       int K, int N)
{
    __shared__ float tile[64][65];
    int n0 = blockIdx.x * 64, k0 = blockIdx.y * 64;
    for (int idx = threadIdx.x; idx < 4096; idx += 256) {
        int rk = idx >> 6, cn = idx & 63;
        tile[rk][cn] = src[(size_t)(k0 + rk) * N + n0 + cn];
    }
    __syncthreads();
    for (int idx = threadIdx.x; idx < 4096; idx += 256) {
        int rn = idx >> 6, ck = idx & 63;
        float v = tile[ck][rn];
        bf16_t hh = (bf16_t)v;
        size_t o = (size_t)(n0 + rn) * K + k0 + ck;
        dhi[o] = hh;
        dlo[o] = (bf16_t)(v - (float)hh);
    }
}

// ---------- x (fp32) -> hi/lo bf16 split, vectorized ----------
__global__ __launch_bounds__(256) void split_x(const float* __restrict__ src,
                                               bf16_t* __restrict__ dhi,
                                               bf16_t* __restrict__ dlo)
{
    size_t i = ((size_t)blockIdx.x * 256 + threadIdx.x) * 8;
    f32x4 a = *(const f32x4*)(src + i);
    f32x4 b = *(const f32x4*)(src + i + 4);
    bf16x8 h, l;
    #pragma unroll
    for (int j = 0; j < 4; j++) {
        bf16_t hh = (bf16_t)a[j]; h[j] = hh; l[j] = (bf16_t)(a[j] - (float)hh);
    }
    #pragma unroll
    for (int j = 0; j < 4; j++) {
        bf16_t hh = (bf16_t)b[j]; h[4 + j] = hh; l[4 + j] = (bf16_t)(b[j] - (float)hh);
    }
    *(bf16x8*)(dhi + i) = h;
    *(bf16x8*)(dlo + i) = l;
}

// ---------- 256x256 8-phase MFMA GEMM over K'=3072 (split-bf16 as 3 K-passes) ----------
// Round-4 changes (schedule/semantics identical to round 3):
//  - LDS dims [op][kh][buf][256][32]: buf stride 16KB -> with compile-time buf
//    (manual x2 K-loop unroll) every ds_read folds to shared vaddr + offset imm.
//  - Staging address = uniform SGPR base (ptr + m0*K + kcol, SALU per tile) +
//    loop-invariant 32-bit lane offset -> saddr+voffset global_load_lds, no VALU.
__global__ __launch_bounds__(512, 2) void gemm8(const bf16_t* __restrict__ Ahi,
                                                const bf16_t* __restrict__ Alo,
                                                const bf16_t* __restrict__ Bhi,
                                                const bf16_t* __restrict__ Blo,
                                                float* __restrict__ C0,
                                                float* __restrict__ Cq,
                                                float* __restrict__ Ck,
                                                float* __restrict__ Cv,
                                                int N, int mode)
{
    __shared__ __align__(16) bf16_t lds[2][2][2][256][32];   // [op][kh][buf][row][col], 128 KiB

    int tid  = threadIdx.x;
    int lane = tid & 63, wv = tid >> 6;
    int wr = wv >> 2, wc = wv & 3;          // 2M x 4N wave grid
    int lm = lane & 15, lk = lane >> 4;

    // bijective XCD swizzle (nwg % 8 == 0 for both launches)
    int nbx  = N >> 8;
    int flat = blockIdx.y * nbx + blockIdx.x;
    int nwg  = nbx * (int)gridDim.y;
    int cpx  = nwg >> 3;
    int swzb = (flat & 7) * cpx + (flat >> 3);
    int m0 = (swzb / nbx) << 8;
    int n0 = (swzb % nbx) << 8;

    // staging lane offsets (loop-invariant VGPRs); T2 source pre-swizzle in ssc8
    int wrow0 = wv << 5;
    int wrow1 = wrow0 + 16;
    int srow  = lane >> 2;
    int ssc8  = (((lane & 3) ^ ((lane >> 3) & 3)) << 3);
    int aoff0 = (wrow0 + srow) * KDIM + ssc8;
    int aoff1 = aoff0 + 16 * KDIM;

    auto stageA = [&](int tt, int kh, int buf) {
        const bf16_t* s = (tt < 32) ? Ahi : Alo;
        const bf16_t* u = s + (size_t)m0 * KDIM + ((tt & 15) << 6) + (kh << 5);
        gld_lds16(u + aoff0, &lds[0][kh][buf][wrow0][0]);
        gld_lds16(u + aoff1, &lds[0][kh][buf][wrow1][0]);
    };
    auto stageB = [&](int tt, int kh, int buf) {
        const bf16_t* s = (tt < 16 || tt >= 32) ? Bhi : Blo;
        const bf16_t* u = s + (size_t)n0 * KDIM + ((tt & 15) << 6) + (kh << 5);
        gld_lds16(u + aoff0, &lds[1][kh][buf][wrow0][0]);
        gld_lds16(u + aoff1, &lds[1][kh][buf][wrow1][0]);
    };

    f32x4 acc[8][4] = {};

    // prologue: prime pipeline; invariant entering t=0:
    // in flight = {(0)Ak1,(0)Bk1,(1)Ak0,(1)Bk0} (8 loads)
    stageA(0, 0, 0); stageB(0, 0, 0);
    stageA(0, 1, 0); stageB(0, 1, 0);
    stageA(1, 0, 1); stageB(1, 0, 1);
    asm volatile("s_waitcnt vmcnt(8)" ::: "memory");
    __builtin_amdgcn_s_barrier();

    int arow = wr * 128 + lm;
    int brow = wc * 64 + lm;
    int kswz = 8 * (lk ^ ((lm >> 1) & 3));   // T2 read-side swizzled column

#define KBODY(T, BUF) do {                                                             \
    bf16x8 afr[4], bfr[4];                                                             \
    /* Phase 0: ksub 0, m-frags 0..3 (+ B frags ks0) */                                \
    _Pragma("unroll")                                                                  \
    for (int i = 0; i < 4; i++)                                                        \
        afr[i] = *(const bf16x8*)&lds[0][0][BUF][arow + i * 16][kswz];                 \
    _Pragma("unroll")                                                                  \
    for (int j = 0; j < 4; j++)                                                        \
        bfr[j] = *(const bf16x8*)&lds[1][0][BUF][brow + j * 16][kswz];                 \
    if ((T) + 1 < KT_N) stageA((T) + 1, 1, (BUF) ^ 1);                                 \
    __builtin_amdgcn_s_barrier();                                                      \
    asm volatile("s_waitcnt lgkmcnt(0)" ::: "memory");                                 \
    __builtin_amdgcn_sched_barrier(0);                                                 \
    __builtin_amdgcn_s_setprio(1);                                                     \
    _Pragma("unroll")                                                                  \
    for (int i = 0; i < 4; i++)                                                        \
        _Pragma("unroll")                                                              \
        for (int j = 0; j < 4; j++)                                                    \
            acc[i][j] = __builtin_amdgcn_mfma_f32_16x16x32_bf16(afr[i], bfr[j], acc[i][j], 0, 0, 0); \
    __builtin_amdgcn_s_setprio(0);                                                     \
    __builtin_amdgcn_sched_barrier(0);                                                 \
    __builtin_amdgcn_s_barrier();                                                      \
    /* Phase 1: ksub 0, m-frags 4..7 */                                                \
    _Pragma("unroll")                                                                  \
    for (int i = 0; i < 4; i++)                                                        \
        afr[i] = *(const bf16x8*)&lds[0][0][BUF][arow + (i + 4) * 16][kswz];           \
    if ((T) + 1 < KT_N) stageB((T) + 1, 1, (BUF) ^ 1);                                 \
    __builtin_amdgcn_s_barrier();                                                      \
    asm volatile("s_waitcnt lgkmcnt(0)" ::: "memory");                                 \
    __builtin_amdgcn_sched_barrier(0);                                                 \
    __builtin_amdgcn_s_setprio(1);                                                     \
    _Pragma("unroll")                                                                  \
    for (int i = 0; i < 4; i++)                                                        \
        _Pragma("unroll")                                                              \
        for (int j = 0; j < 4; j++)                                                    \
            acc[i + 4][j] = __builtin_amdgcn_mfma_f32_16x16x32_bf16(afr[i], bfr[j], acc[i + 4][j], 0, 0, 0); \
    __builtin_amdgcn_s_setprio(0);                                                     \
    __builtin_amdgcn_sched_barrier(0);                                                 \
    if ((T) + 1 < KT_N) { asm volatile("s_waitcnt vmcnt(8)" ::: "memory"); }           \
    else                { asm volatile("s_waitcnt vmcnt(0)" ::: "memory"); }           \
    __builtin_amdgcn_s_barrier();                                                      \
    /* Phase 2: ksub 1, m-frags 0..3 (+ B frags ks1) */                                \
    _Pragma("unroll")                                                                  \
    for (int i = 0; i < 4; i++)                                                        \
        afr[i] = *(const bf16x8*)&lds[0][1][BUF][arow + i * 16][kswz];                 \
    _Pragma("unroll")                                                                  \
    for (int j = 0; j < 4; j++)                                                        \
        bfr[j] = *(const bf16x8*)&lds[1][1][BUF][brow + j * 16][kswz];                 \
    if ((T) + 2 < KT_N) stageA((T) + 2, 0, BUF);                                       \
    __builtin_amdgcn_s_barrier();                                                      \
    asm volatile("s_waitcnt lgkmcnt(0)" ::: "memory");                                 \
    __builtin_amdgcn_sched_barrier(0);                                                 \
    __builtin_amdgcn_s_setprio(1);                                                     \
    _Pragma("unroll")                                                                  \
    for (int i = 0; i < 4; i++)                                                        \
        _Pragma("unroll")                                                              \
        for (int j = 0; j < 4; j++)                                                    \
            acc[i][j] = __builtin_amdgcn_mfma_f32_16x16x32_bf16(afr[i], bfr[j], acc[i][j], 0, 0, 0); \
    __builtin_amdgcn_s_setprio(0);                                                     \
    __builtin_amdgcn_sched_barrier(0);                                                 \
    __builtin_amdgcn_s_barrier();                                                      \
    /* Phase 3: ksub 1, m-frags 4..7 */                                                \
    _Pragma("unroll")                                                                  \
    for (int i = 0; i < 4; i++)                                                        \
        afr[i] = *(const bf16x8*)&lds[0][1][BUF][arow + (i + 4) * 16][kswz];           \
    if ((T) + 2 < KT_N) stageB((T) + 2, 0, BUF);                                       \
    __builtin_amdgcn_s_barrier();                                                      \
    asm volatile("s_waitcnt lgkmcnt(0)" ::: "memory");                                 \
    __builtin_amdgcn_sched_barrier(0);                                                 \
    __builtin_amdgcn_s_setprio(1);                                                     \
    _Pragma("unroll")                                                                  \
    for (int i = 0; i < 4; i++)                                                        \
        _Pragma("unroll")                                                              \
        for (int j = 0; j < 4; j++)                                                    \
            acc[i + 4][j] = __builtin_amdgcn_mfma_f32_16x16x32_bf16(afr[i], bfr[j], acc[i + 4][j], 0, 0, 0); \
    __builtin_amdgcn_s_setprio(0);                                                     \
    __builtin_amdgcn_sched_barrier(0);                                                 \
    if ((T) + 2 < KT_N)      { asm volatile("s_waitcnt vmcnt(8)" ::: "memory"); }      \
    else if ((T) + 1 < KT_N) { asm volatile("s_waitcnt vmcnt(4)" ::: "memory"); }      \
    __builtin_amdgcn_s_barrier();                                                      \
} while (0)

    for (int u = 0; u < KT_N / 2; ++u) {
        KBODY(2 * u, 0);
        KBODY(2 * u + 1, 1);
    }
#undef KBODY

    // ---- epilogue: C/D layout col=lane&15, row=(lane>>4)*4+reg ----
    if (mode == 0) {
        #pragma unroll
        for (int fm = 0; fm < 8; fm++) {
            int grow0 = m0 + wr * 128 + fm * 16 + lk * 4;
            #pragma unroll
            for (int fn = 0; fn < 4; fn++) {
                int gcol = n0 + wc * 64 + fn * 16 + lm;
                #pragma unroll
                for (int reg = 0; reg < 4; reg++)
                    C0[(size_t)(grow0 + reg) * N + gcol] = acc[fm][fn][reg];
            }
        }
    } else {
        #pragma unroll
        for (int fm = 0; fm < 8; fm++) {
            int grow0 = m0 + wr * 128 + fm * 16 + lk * 4;
            #pragma unroll
            for (int fn = 0; fn < 4; fn++) {
                int n = n0 + wc * 64 + fn * 16 + lm;
                float* dst; int nn;
                if (n < 1024)      { dst = Cq; nn = n; }
                else if (n < 2048) { dst = Ck; nn = n - 1024; }
                else               { dst = Cv; nn = n - 2048; }
                int hh = nn >> 6, d = nn & 63;
                #pragma unroll
                for (int reg = 0; reg < 4; reg++) {
                    int m = grow0 + reg;
                    int b = m >> 12, tt2 = m & 4095;
                    dst[(((size_t)(b * NH + hh)) * SEQ + tt2) * HS + d] = acc[fm][fn][reg];
                }
            }
        }
    }
}

// ---------------- landmarks ----------------
__global__ __launch_bounds__(256) void landmark_kernel(const float* __restrict__ q,
                                                       const float* __restrict__ k,
                                                       float* __restrict__ ql,
                                                       float* __restrict__ kl)
{
    int idx = blockIdx.x * 256 + threadIdx.x;
    int d = idx & 63, l = (idx >> 6) & 63, bh = idx >> 12;
    const float* qp = q + (((size_t)bh * SEQ) + l * 64) * HS + d;
    const float* kp = k + (((size_t)bh * SEQ) + l * 64) * HS + d;
    float sq = 0.f, sk = 0.f;
    for (int t = 0; t < 64; t++) { sq += qp[t * HS]; sk += kp[t * HS]; }
    ql[idx] = sq * (1.0f / 64.0f);
    kl[idx] = sk * (1.0f / 64.0f);
}

// ---------------- pinv (all-LDS Newton-Schulz, 4x4 register-tiled) ----------------
// Conflict-free transposes: staging via 4-strided-reads -> f32x4 row writes;
// in-loop transposed tiles stored as per-j f32x4 rows (b128-floor banks).
#define PPAD 68
__global__ __launch_bounds__(256) void pinv_kernel(const float* __restrict__ ql,
                                                   const float* __restrict__ kl,
                                                   float* __restrict__ Pbuf)
{
    int bh = blockIdx.x;
    __shared__ float AsmM[64][PPAD], AsmT[64][PPAD], V[64][PPAD], VT[64][PPAD],
                     KV[64][PPAD], KVT[64][PPAD], Tb[64][PPAD];
    __shared__ float colsum[64];
    __shared__ float denom_s;
    int tid = threadIdx.x;
    int ri = tid >> 4, cj = tid & 15;
    int r0 = ri * 4, c0 = cj * 4;

    // stage qlT into KV, klT into KVT (conflict-free b128 writes)
    {
        int sd = tid & 63, srg = tid >> 6;
        const float* qp = ql + (size_t)bh * 4096;
        const float* kp = kl + (size_t)bh * 4096;
        float bq[16], bk[16];
        #pragma unroll
        for (int j = 0; j < 16; j++) {
            bq[j] = qp[(srg * 16 + j) * 64 + sd];
            bk[j] = kp[(srg * 16 + j) * 64 + sd];
        }
        #pragma unroll
        for (int jj = 0; jj < 4; jj++) {
            f32x4 t1 = { bq[4 * jj], bq[4 * jj + 1], bq[4 * jj + 2], bq[4 * jj + 3] };
            f32x4 t2 = { bk[4 * jj], bk[4 * jj + 1], bk[4 * jj + 2], bk[4 * jj + 3] };
            *(f32x4*)&KV[sd][srg * 16 + 4 * jj]  = t1;
            *(f32x4*)&KVT[sd][srg * 16 + 4 * jj] = t2;
        }
    }
    __syncthreads();

    // scores S = ql @ kl^T (4x4 tile per thread)
    float c[4][4] = {};
    for (int d = 0; d < 64; d++) {
        f32x4 a = *(const f32x4*)&KV[d][r0];
        f32x4 b = *(const f32x4*)&KVT[d][c0];
        #pragma unroll
        for (int i = 0; i < 4; i++)
            #pragma unroll
            for (int j = 0; j < 4; j++) c[i][j] += a[i] * b[j];
    }
    // rowwise softmax (rows split across the 16-lane cj group)
    #pragma unroll
    for (int i = 0; i < 4; i++) {
        float tmax = fmaxf(fmaxf(c[i][0], c[i][1]), fmaxf(c[i][2], c[i][3]));
        #pragma unroll
        for (int off = 1; off < 16; off <<= 1)
            tmax = fmaxf(tmax, __shfl_xor(tmax, off, 64));
        float psum = 0.f;
        #pragma unroll
        for (int j = 0; j < 4; j++) {
            float p = expf(c[i][j] - tmax);
            c[i][j] = p; psum += p;
        }
        #pragma unroll
        for (int off = 1; off < 16; off <<= 1)
            psum += __shfl_xor(psum, off, 64);
        float inv = 1.0f / psum;
        #pragma unroll
        for (int j = 0; j < 4; j++) c[i][j] *= inv;
    }
    __syncthreads();
    #pragma unroll
    for (int i = 0; i < 4; i++)
        *(f32x4*)&AsmM[r0 + i][c0] = *(f32x4*)&c[i][0];
    #pragma unroll
    for (int j = 0; j < 4; j++) {
        f32x4 t = { c[0][j], c[1][j], c[2][j], c[3][j] };
        *(f32x4*)&AsmT[c0 + j][r0] = t;
    }
    __syncthreads();

    // denom = max over columns of column-sums; colsum[c] = sum of AsmT row c
    if (tid < 64) {
        float cs = 0.f;
        for (int x = 0; x < 64; x += 4) {
            f32x4 t = *(const f32x4*)&AsmT[tid][x];
            cs += t[0] + t[1] + t[2] + t[3];
        }
        colsum[tid] = cs;
    }
    __syncthreads();
    if (tid == 0) {
        float mx = colsum[0];
        for (int j = 1; j < 64; j++) mx = fmaxf(mx, colsum[j]);
        denom_s = mx;
    }
    __syncthreads();
    {
        float dinv = 1.0f / denom_s;
        #pragma unroll
        for (int i = 0; i < 4; i++) {
            f32x4 t = *(const f32x4*)&AsmT[r0 + i][c0];
            f32x4 o = t * dinv;
            *(f32x4*)&V[r0 + i][c0] = o;
        }
        #pragma unroll
        for (int j = 0; j < 4; j++) {
            // VT[c][r] = V[r][c]; V-tile rows r0+i live in AsmT[r0+i][c0+j] scaled
            f32x4 t = { AsmT[r0 + 0][c0 + j] * dinv, AsmT[r0 + 1][c0 + j] * dinv,
                        AsmT[r0 + 2][c0 + j] * dinv, AsmT[r0 + 3][c0 + j] * dinv };
            *(f32x4*)&VT[c0 + j][r0] = t;
        }
    }
    __syncthreads();

    float u[4][4];
    for (int it = 0; it < 6; it++) {
        // M1: KV = Asm @ V
        #pragma unroll
        for (int i = 0; i < 4; i++)
            #pragma unroll
            for (int j = 0; j < 4; j++) c[i][j] = 0.f;
        for (int kx = 0; kx < 64; kx++) {
            f32x4 a = *(const f32x4*)&AsmT[kx][r0];
            f32x4 b = *(const f32x4*)&V[kx][c0];
            #pragma unroll
            for (int i = 0; i < 4; i++)
                #pragma unroll
                for (int j = 0; j < 4; j++) c[i][j] += a[i] * b[j];
        }
        __syncthreads();
        #pragma unroll
        for (int i = 0; i < 4; i++)
            *(f32x4*)&KV[r0 + i][c0] = *(f32x4*)&c[i][0];
        #pragma unroll
        for (int j = 0; j < 4; j++) {
            f32x4 t = { c[0][j], c[1][j], c[2][j], c[3][j] };
            *(f32x4*)&KVT[c0 + j][r0] = t;
        }
        #pragma unroll
        for (int i = 0; i < 4; i++) {
            f32x4 t;
            #pragma unroll
            for (int j = 0; j < 4; j++)
                t[j] = ((r0 + i) == (c0 + j) ? 7.0f : 0.0f) - c[i][j];
            *(f32x4*)&Tb[r0 + i][c0] = t;
        }
        __syncthreads();
        // M2: U = KV @ T1
        #pragma unroll
        for (int i = 0; i < 4; i++)
            #pragma unroll
            for (int j = 0; j < 4; j++) u[i][j] = 0.f;
        for (int kx = 0; kx < 64; kx++) {
            f32x4 a = *(const f32x4*)&KVT[kx][r0];
            f32x4 b = *(const f32x4*)&Tb[kx][c0];
            #pragma unroll
            for (int i = 0; i < 4; i++)
                #pragma unroll
                for (int j = 0; j < 4; j++) u[i][j] += a[i] * b[j];
        }
        __syncthreads();
        #pragma unroll
        for (int i = 0; i < 4; i++) {
            f32x4 t;
            #pragma unroll
            for (int j = 0; j < 4; j++)
                t[j] = ((r0 + i) == (c0 + j) ? 15.0f : 0.0f) - u[i][j];
            *(f32x4*)&Tb[r0 + i][c0] = t;
        }
        __syncthreads();
        // M3: U2 = KV @ T2
        #pragma unroll
        for (int i = 0; i < 4; i++)
            #pragma unroll
            for (int j = 0; j < 4; j++) u[i][j] = 0.f;
        for (int kx = 0; kx < 64; kx++) {
            f32x4 a = *(const f32x4*)&KVT[kx][r0];
            f32x4 b = *(const f32x4*)&Tb[kx][c0];
            #pragma unroll
            for (int i = 0; i < 4; i++)
                #pragma unroll
                for (int j = 0; j < 4; j++) u[i][j] += a[i] * b[j];
        }
        __syncthreads();
        #pragma unroll
        for (int i = 0; i < 4; i++) {
            f32x4 t;
            #pragma unroll
            for (int j = 0; j < 4; j++)
                t[j] = ((r0 + i) == (c0 + j) ? 13.0f : 0.0f) - u[i][j];
            *(f32x4*)&Tb[r0 + i][c0] = t;
        }
        __syncthreads();
        // M4: Vn = 0.25 * V @ T3
        #pragma unroll
        for (int i = 0; i < 4; i++)
            #pragma unroll
            for (int j = 0; j < 4; j++) c[i][j] = 0.f;
        for (int kx = 0; kx < 64; kx++) {
            f32x4 a = *(const f32x4*)&VT[kx][r0];
            f32x4 b = *(const f32x4*)&Tb[kx][c0];
            #pragma unroll
            for (int i = 0; i < 4; i++)
                #pragma unroll
                for (int j = 0; j < 4; j++) c[i][j] += a[i] * b[j];
        }
        __syncthreads();
        #pragma unroll
        for (int i = 0; i < 4; i++) {
            f32x4 o;
            #pragma unroll
            for (int j = 0; j < 4; j++) o[j] = 0.25f * c[i][j];
            *(f32x4*)&V[r0 + i][c0] = o;
        }
        #pragma unroll
        for (int j = 0; j < 4; j++) {
            f32x4 t = { 0.25f * c[0][j], 0.25f * c[1][j], 0.25f * c[2][j], 0.25f * c[3][j] };
            *(f32x4*)&VT[c0 + j][r0] = t;
        }
        __syncthreads();
    }
    #pragma unroll
    for (int i = 0; i < 4; i++)
        *(f32x4*)&Pbuf[(size_t)bh * 4096 + (r0 + i) * 64 + c0] = *(const f32x4*)&V[r0 + i][c0];
}

// ---------------- N path phase 1: per (bh, 256-wide t-chunk) partials ----------------
#define NVP 68
__global__ __launch_bounds__(256) void nv_partial(const float* __restrict__ ql,
                                                  const float* __restrict__ k,
                                                  const float* __restrict__ v,
                                                  float* __restrict__ pm,
                                                  float* __restrict__ ps,
                                                  float* __restrict__ pacc)
{
    int bh = blockIdx.y;
    int c0 = blockIdx.x;
    int tid = threadIdx.x;
    int rg = tid >> 4, tg = tid & 15;
    int sd = tid & 63, srg = tid >> 6;
    __shared__ float qlT[64][NVP];
    __shared__ float kT[64][NVP];
    __shared__ float vch[64][NVP];
    __shared__ float pchT[64][NVP];   // [t][l-row]: P transposed for f32x4 PV reads

    {
        const float* qp = ql + (size_t)bh * 4096;
        float bq[16];
        #pragma unroll
        for (int j = 0; j < 16; j++) bq[j] = qp[(srg * 16 + j) * 64 + sd];
        #pragma unroll
        for (int jj = 0; jj < 4; jj++) {
            f32x4 t = { bq[4 * jj], bq[4 * jj + 1], bq[4 * jj + 2], bq[4 * jj + 3] };
            *(f32x4*)&qlT[sd][srg * 16 + 4 * jj] = t;
        }
    }

    float m_r[4], s_r[4];
    float acc[4][4];
    #pragma unroll
    for (int i = 0; i < 4; i++) {
        m_r[i] = -1e30f; s_r[i] = 0.f;
        #pragma unroll
        for (int j = 0; j < 4; j++) acc[i][j] = 0.f;
    }

    for (int sc = 0; sc < 4; sc++) {
        __syncthreads();
        const float* kp = k + ((size_t)bh * SEQ + c0 * 256 + sc * 64) * HS;
        const float* vp = v + ((size_t)bh * SEQ + c0 * 256 + sc * 64) * HS;
        {
            float bk[16];
            #pragma unroll
            for (int j = 0; j < 16; j++) bk[j] = kp[(srg * 16 + j) * 64 + sd];
            #pragma unroll
            for (int jj = 0; jj < 4; jj++) {
                f32x4 t = { bk[4 * jj], bk[4 * jj + 1], bk[4 * jj + 2], bk[4 * jj + 3] };
                *(f32x4*)&kT[sd][srg * 16 + 4 * jj] = t;
            }
        }
        for (int i = tid; i < 4096; i += 256)
            vch[i >> 6][i & 63] = vp[i];
        __syncthreads();

        float s[4][4] = {};
        #pragma unroll 4
        for (int dd = 0; dd < 64; dd++) {
            f32x4 a = *(const f32x4*)&qlT[dd][rg * 4];
            f32x4 b = *(const f32x4*)&kT[dd][tg * 4];
            #pragma unroll
            for (int i = 0; i < 4; i++)
                #pragma unroll
                for (int j = 0; j < 4; j++) s[i][j] += a[i] * b[j];
        }

        #pragma unroll
        for (int i = 0; i < 4; i++) {
            float tmax = fmaxf(fmaxf(s[i][0], s[i][1]), fmaxf(s[i][2], s[i][3]));
            #pragma unroll
            for (int off = 1; off < 16; off <<= 1)
                tmax = fmaxf(tmax, __shfl_xor(tmax, off, 64));
            float mnew = fmaxf(m_r[i], tmax);
            float alpha = expf(m_r[i] - mnew);
            m_r[i] = mnew;
            float psum = 0.f;
            #pragma unroll
            for (int j = 0; j < 4; j++) {
                float p = expf(s[i][j] - mnew);
                s[i][j] = p;
                psum += p;
            }
            #pragma unroll
            for (int off = 1; off < 16; off <<= 1)
                psum += __shfl_xor(psum, off, 64);
            s_r[i] = s_r[i] * alpha + psum;
            #pragma unroll
            for (int j = 0; j < 4; j++) acc[i][j] *= alpha;
        }
        // transposed P store as f32x4 rows (conflict-free)
        #pragma unroll
        for (int j = 0; j < 4; j++) {
            f32x4 t = { s[0][j], s[1][j], s[2][j], s[3][j] };
            *(f32x4*)&pchT[tg * 4 + j][rg * 4] = t;
        }
        __syncthreads();

        // PV: acc[i][j] += sum_t P[row_i][t] * v[t][d_j]  (2x b128 per t)
        #pragma unroll 2
        for (int tt = 0; tt < 64; tt++) {
            f32x4 vv = *(const f32x4*)&vch[tt][tg * 4];
            f32x4 pr = *(const f32x4*)&pchT[tt][rg * 4];
            #pragma unroll
            for (int i = 0; i < 4; i++)
                #pragma unroll
                for (int j = 0; j < 4; j++)
                    acc[i][j] += pr[i] * vv[j];
        }
    }

    float* paccp = pacc + ((((size_t)bh * 16 + c0) * 64) + rg * 4) * 64 + tg * 4;
    #pragma unroll
    for (int i = 0; i < 4; i++)
        *(f32x4*)&paccp[(size_t)i * 64] = *(f32x4*)&acc[i][0];
    if (tg == 0) {
        #pragma unroll
        for (int i = 0; i < 4; i++) {
            pm[((size_t)bh * 16 + c0) * 64 + rg * 4 + i] = m_r[i];
            ps[((size_t)bh * 16 + c0) * 64 + rg * 4 + i] = s_r[i];
        }
    }
}

// ---------------- N path phase 2 + PNv, fused: Nv in LDS, PNv = P @ Nv ----------------
__global__ __launch_bounds__(256) void combine_pnv(const float* __restrict__ pm,
                                                   const float* __restrict__ ps,
                                                   const float* __restrict__ pacc,
                                                   const float* __restrict__ P,
                                                   float* __restrict__ PNv)
{
    int bh = blockIdx.x;
    int tid = threadIdx.x;
    __shared__ float NvS[64][NVP];
    __shared__ float PT[64][NVP];

    // stage P transposed (conflict-free)
    {
        int sd = tid & 63, srg = tid >> 6;
        const float* pb = P + (size_t)bh * 4096;
        float bp[16];
        #pragma unroll
        for (int j = 0; j < 16; j++) bp[j] = pb[(srg * 16 + j) * 64 + sd];
        #pragma unroll
        for (int jj = 0; jj < 4; jj++) {
            f32x4 t = { bp[4 * jj], bp[4 * jj + 1], bp[4 * jj + 2], bp[4 * jj + 3] };
            *(f32x4*)&PT[sd][srg * 16 + 4 * jj] = t;
        }
    }

    // combine 16 chunk partials -> Nv row in LDS
    {
        int l = tid >> 2, dq = tid & 3;
        float m16[16];
        float gm = -1e30f;
        #pragma unroll
        for (int c = 0; c < 16; c++) {
            m16[c] = pm[((size_t)bh * 16 + c) * 64 + l];
            gm = fmaxf(gm, m16[c]);
        }
        float gs = 0.f;
        float e16[16];
        #pragma unroll
        for (int c = 0; c < 16; c++) {
            float e = expf(m16[c] - gm);
            e16[c] = e;
            gs += ps[((size_t)bh * 16 + c) * 64 + l] * e;
        }
        f32x4 a[4] = {};
        for (int c = 0; c < 16; c++) {
            float e = e16[c];
            const float* pp = pacc + (((size_t)bh * 16 + c) * 64 + l) * 64 + dq * 16;
            #pragma unroll
            for (int i = 0; i < 4; i++) {
                f32x4 t = *(const f32x4*)&pp[4 * i];
                a[i] += e * t;
            }
        }
        float inv = 1.0f / gs;
        #pragma unroll
        for (int i = 0; i < 4; i++) {
            f32x4 o = a[i] * inv;
            *(f32x4*)&NvS[l][dq * 16 + 4 * i] = o;
        }
    }
    __syncthreads();

    // PNv = P @ Nv (4x4 register tiles)
    int ri = tid >> 4, cj = tid & 15;
    int r0 = ri * 4, c0 = cj * 4;
    float c[4][4] = {};
    for (int kx = 0; kx < 64; kx++) {
        f32x4 a = *(const f32x4*)&PT[kx][r0];
        f32x4 b = *(const f32x4*)&NvS[kx][c0];
        #pragma unroll
        for (int i = 0; i < 4; i++)
            #pragma unroll
            for (int j = 0; j < 4; j++) c[i][j] += a[i] * b[j];
    }
    #pragma unroll
    for (int i = 0; i < 4; i++)
        *(f32x4*)&PNv[(size_t)bh * 4096 + (r0 + i) * 64 + c0] = *(f32x4*)&c[i][0];
}

// ---------------- y = softmax(q @ kl^T) @ PNv -> hi/lo bf16 (B,T,C) ----------------
__global__ __launch_bounds__(256) void y_kernel(const float* __restrict__ q,
                                                const float* __restrict__ kl,
                                                const float* __restrict__ PNv,
                                                bf16_t* __restrict__ yhi,
                                                bf16_t* __restrict__ ylo)
{
    int bh = blockIdx.y;
    int t0 = blockIdx.x * 64;
    int tid = threadIdx.x;
    __shared__ float qT[64][NVP], klT[64][NVP], pnv[64][NVP], pT[64][NVP];
    const float* qp = q + ((size_t)bh * SEQ + t0) * HS;
    const float* kp = kl + (size_t)bh * 4096;
    const float* pp = PNv + (size_t)bh * 4096;
    {
        int sd = tid & 63, srg = tid >> 6;
        float bq[16], bk[16];
        #pragma unroll
        for (int j = 0; j < 16; j++) {
            bq[j] = qp[(srg * 16 + j) * 64 + sd];
            bk[j] = kp[(srg * 16 + j) * 64 + sd];
        }
        #pragma unroll
        for (int jj = 0; jj < 4; jj++) {
            f32x4 t1 = { bq[4 * jj], bq[4 * jj + 1], bq[4 * jj + 2], bq[4 * jj + 3] };
            f32x4 t2 = { bk[4 * jj], bk[4 * jj + 1], bk[4 * jj + 2], bk[4 * jj + 3] };
            *(f32x4*)&qT[sd][srg * 16 + 4 * jj]  = t1;
            *(f32x4*)&klT[sd][srg * 16 + 4 * jj] = t2;
        }
        for (int i = tid; i < 4096; i += 256)
            pnv[i >> 6][i & 63] = pp[i];
    }
    __syncthreads();

    int ti = tid >> 4, gj = tid & 15;
    int r0 = ti * 4, c0 = gj * 4;

    // scores S[4t][4l]
    float s[4][4] = {};
    for (int d = 0; d < 64; d++) {
        f32x4 a = *(const f32x4*)&qT[d][r0];
        f32x4 b = *(const f32x4*)&klT[d][c0];
        #pragma unroll
        for (int i = 0; i < 4; i++)
            #pragma unroll
            for (int j = 0; j < 4; j++) s[i][j] += a[i] * b[j];
    }
    // row softmax across 16-lane gj group
    #pragma unroll
    for (int i = 0; i < 4; i++) {
        float tmax = fmaxf(fmaxf(s[i][0], s[i][1]), fmaxf(s[i][2], s[i][3]));
        #pragma unroll
        for (int off = 1; off < 16; off <<= 1)
            tmax = fmaxf(tmax, __shfl_xor(tmax, off, 64));
        float psum = 0.f;
        #pragma unroll
        for (int j = 0; j < 4; j++) {
            float p = expf(s[i][j] - tmax);
            s[i][j] = p; psum += p;
        }
        #pragma unroll
        for (int off = 1; off < 16; off <<= 1)
            psum += __shfl_xor(psum, off, 64);
        float inv = 1.0f / psum;
        #pragma unroll
        for (int j = 0; j < 4; j++) s[i][j] *= inv;
    }
    #pragma unroll
    for (int j = 0; j < 4; j++) {
        f32x4 t = { s[0][j], s[1][j], s[2][j], s[3][j] };
        *(f32x4*)&pT[c0 + j][r0] = t;
    }
    __syncthreads();

    // PV: out[4t][4d], d-cols c0..
    float o[4][4] = {};
    for (int l = 0; l < 64; l++) {
        f32x4 a = *(const f32x4*)&pT[l][r0];
        f32x4 b = *(const f32x4*)&pnv[l][c0];
        #pragma unroll
        for (int i = 0; i < 4; i++)
            #pragma unroll
            for (int j = 0; j < 4; j++) o[i][j] += a[i] * b[j];
    }

    int b = bh >> 4, h = bh & 15;
    #pragma unroll
    for (int i = 0; i < 4; i++) {
        bf16x4 hv, lv;
        #pragma unroll
        for (int j = 0; j < 4; j++) {
            float v = o[i][j];
            bf16_t hh = (bf16_t)v;
            hv[j] = hh;
            lv[j] = (bf16_t)(v - (float)hh);
        }
        size_t oo = ((size_t)(b * SEQ) + t0 + r0 + i) * CDIM + h * HS + c0;
        *(bf16x4*)(yhi + oo) = hv;
        *(bf16x4*)(ylo + oo) = lv;
    }
}

// ---------------- launch ----------------
extern "C" void kernel_launch(void* const* d_in, const int* in_sizes, int n_in,
                              void* d_out, int out_size, void* d_ws, size_t ws_size,
                              hipStream_t stream)
{
    const float* x  = (const float*)d_in[0];
    const float* Wa = (const float*)d_in[1];
    const float* Wp = (const float*)d_in[2];
    float* out = (float*)d_out;
    float* W = (float*)d_ws;

    const size_t off_q    = 0;
    const size_t off_k    = 16777216;
    const size_t off_v    = 33554432;
    const size_t off_ql   = 50331648;
    const size_t off_kl   = off_ql + 262144;
    const size_t off_P    = off_kl + 262144;
    const size_t off_Nv   = off_P  + 262144;
    const size_t off_PNv  = off_Nv + 262144;
    const size_t off_WatH = off_PNv + 262144;
    const size_t off_WatL = off_WatH + 1572864;
    const size_t off_WptH = off_WatL + 1572864;
    const size_t off_WptL = off_WptH + 524288;
    const size_t off_pm   = off_WptL + 524288;
    const size_t off_ps   = off_pm + 65536;
    const size_t off_pacc = off_ps + 65536;
    const size_t need = (off_pacc + 4194304) * sizeof(float);
    if (ws_size < need) {
        fprintf(stderr, "[nystrom] ws too small: have %zu need %zu\n", ws_size, need);
        return;
    }

    float* q    = W + off_q;
    float* k    = W + off_k;
    float* v    = W + off_v;
    float* ql   = W + off_ql;
    float* kl   = W + off_kl;
    float* P    = W + off_P;
    float* PNv  = W + off_PNv;
    bf16_t* WatH = (bf16_t*)(W + off_WatH);
    bf16_t* WatL = (bf16_t*)(W + off_WatL);
    bf16_t* WptH = (bf16_t*)(W + off_WptH);
    bf16_t* WptL = (bf16_t*)(W + off_WptL);
    float* pm   = W + off_pm;
    float* ps   = W + off_ps;
    float* pacc = W + off_pacc;
    bf16_t* yhi = (bf16_t*)(W + off_k);       // alias k (dead after nv_partial)
    bf16_t* ylo = yhi + (size_t)MROWS * CDIM;
    bf16_t* xhi = (bf16_t*)d_out;             // d_out scratch until final GEMM
    bf16_t* xlo = xhi + (size_t)MROWS * KDIM;

    transpose_split<<<dim3(N3 / 64, KDIM / 64), 256, 0, stream>>>(Wa, WatH, WatL, KDIM, N3);
    transpose_split<<<dim3(CDIM / 64, KDIM / 64), 256, 0, stream>>>(Wp, WptH, WptL, KDIM, CDIM);
    split_x<<<(MROWS * KDIM) / (256 * 8), 256, 0, stream>>>(x, xhi, xlo);
    gemm8<<<dim3(N3 / 256, MROWS / 256), 512, 0, stream>>>(xhi, xlo, WatH, WatL,
                                                           nullptr, q, k, v, N3, 1);
    landmark_kernel<<<262144 / 256, 256, 0, stream>>>(q, k, ql, kl);
    pinv_kernel<<<64, 256, 0, stream>>>(ql, kl, P);
    nv_partial<<<dim3(16, 64), 256, 0, stream>>>(ql, k, v, pm, ps, pacc);
    combine_pnv<<<64, 256, 0, stream>>>(pm, ps, pacc, P, PNv);
    y_kernel<<<dim3(64, 64), 256, 0, stream>>>(q, kl, PNv, yhi, ylo);
    gemm8<<<dim3(CDIM / 256, MROWS / 256), 512, 0, stream>>>(yhi, ylo, WptH, WptL,
                                                             out, nullptr, nullptr, nullptr, CDIM, 0);
}

// Round 7
// 729.623 us; speedup vs baseline: 1.5681x; 1.0468x over previous
//
#include <hip/hip_runtime.h>
#include <hip/hip_bf16.h>
#include <cstdio>
#include <cstdint>

#define BATCH 4
#define SEQ   4096
#define CDIM  1024
#define NH    16
#define HS    64
#define NL    64
#define MROWS 16384
#define N3    3072
#define KDIM  1024
#define KT_N  48   // K' = 3*1024 / 64

typedef __bf16 bf16_t;
typedef bf16_t bf16x8 __attribute__((ext_vector_type(8)));
typedef bf16_t bf16x4 __attribute__((ext_vector_type(4)));
typedef float  f32x4  __attribute__((ext_vector_type(4)));

__device__ __forceinline__ void gld_lds16(const void* g, void* l)
{
    __builtin_amdgcn_global_load_lds((__attribute__((address_space(1))) void*)(void*)g,
                                     (__attribute__((address_space(3))) void*)l,
                                     16, 0, 0);
}

// ---------- W transpose + hi/lo bf16 split: dst[n][k] = split(src[k][n]) ----------
__global__ __launch_bounds__(256) void transpose_split(const float* __restrict__ src,
                                                       bf16_t* __restrict__ dhi,
                                                       bf16_t* __restrict__ dlo,
                                                       int K, int N)
{
    __shared__ float tile[64][65];
    int n0 = blockIdx.x * 64, k0 = blockIdx.y * 64;
    for (int idx = threadIdx.x; idx < 4096; idx += 256) {
        int rk = idx >> 6, cn = idx & 63;
        tile[rk][cn] = src[(size_t)(k0 + rk) * N + n0 + cn];
    }
    __syncthreads();
    for (int idx = threadIdx.x; idx < 4096; idx += 256) {
        int rn = idx >> 6, ck = idx & 63;
        float v = tile[ck][rn];
        bf16_t hh = (bf16_t)v;
        size_t o = (size_t)(n0 + rn) * K + k0 + ck;
        dhi[o] = hh;
        dlo[o] = (bf16_t)(v - (float)hh);
    }
}

// ---------- x (fp32) -> hi/lo bf16 split, vectorized ----------
__global__ __launch_bounds__(256) void split_x(const float* __restrict__ src,
                                               bf16_t* __restrict__ dhi,
                                               bf16_t* __restrict__ dlo)
{
    size_t i = ((size_t)blockIdx.x * 256 + threadIdx.x) * 8;
    f32x4 a = *(const f32x4*)(src + i);
    f32x4 b = *(const f32x4*)(src + i + 4);
    bf16x8 h, l;
    #pragma unroll
    for (int j = 0; j < 4; j++) {
        bf16_t hh = (bf16_t)a[j]; h[j] = hh; l[j] = (bf16_t)(a[j] - (float)hh);
    }
    #pragma unroll
    for (int j = 0; j < 4; j++) {
        bf16_t hh = (bf16_t)b[j]; h[4 + j] = hh; l[4 + j] = (bf16_t)(b[j] - (float)hh);
    }
    *(bf16x8*)(dhi + i) = h;
    *(bf16x8*)(dlo + i) = l;
}

// ---------- 256x256 8-phase MFMA GEMM over K'=3072 (split-bf16 as 3 K-passes) ----------
// Round-6 addition: mode-1 epilogue also emits landmarks (window mean over t)
// directly from acc registers -> landmark_kernel dispatch eliminated.
__global__ __launch_bounds__(512, 2) void gemm8(const bf16_t* __restrict__ Ahi,
                                                const bf16_t* __restrict__ Alo,
                                                const bf16_t* __restrict__ Bhi,
                                                const bf16_t* __restrict__ Blo,
                                                float* __restrict__ C0,
                                                float* __restrict__ Cq,
                                                float* __restrict__ Ck,
                                                float* __restrict__ Cv,
                                                float* __restrict__ ql_out,
                                                float* __restrict__ kl_out,
                                                int N, int mode)
{
    __shared__ __align__(16) bf16_t lds[2][2][2][256][32];   // [op][kh][buf][row][col], 128 KiB

    int tid  = threadIdx.x;
    int lane = tid & 63, wv = tid >> 6;
    int wr = wv >> 2, wc = wv & 3;          // 2M x 4N wave grid
    int lm = lane & 15, lk = lane >> 4;

    // bijective XCD swizzle (nwg % 8 == 0 for both launches)
    int nbx  = N >> 8;
    int flat = blockIdx.y * nbx + blockIdx.x;
    int nwg  = nbx * (int)gridDim.y;
    int cpx  = nwg >> 3;
    int swzb = (flat & 7) * cpx + (flat >> 3);
    int m0 = (swzb / nbx) << 8;
    int n0 = (swzb % nbx) << 8;

    // staging lane offsets (loop-invariant VGPRs); T2 source pre-swizzle in ssc8
    int wrow0 = wv << 5;
    int wrow1 = wrow0 + 16;
    int srow  = lane >> 2;
    int ssc8  = (((lane & 3) ^ ((lane >> 3) & 3)) << 3);
    int aoff0 = (wrow0 + srow) * KDIM + ssc8;
    int aoff1 = aoff0 + 16 * KDIM;

    auto stageA = [&](int tt, int kh, int buf) {
        const bf16_t* s = (tt < 32) ? Ahi : Alo;
        const bf16_t* u = s + (size_t)m0 * KDIM + ((tt & 15) << 6) + (kh << 5);
        gld_lds16(u + aoff0, &lds[0][kh][buf][wrow0][0]);
        gld_lds16(u + aoff1, &lds[0][kh][buf][wrow1][0]);
    };
    auto stageB = [&](int tt, int kh, int buf) {
        const bf16_t* s = (tt < 16 || tt >= 32) ? Bhi : Blo;
        const bf16_t* u = s + (size_t)n0 * KDIM + ((tt & 15) << 6) + (kh << 5);
        gld_lds16(u + aoff0, &lds[1][kh][buf][wrow0][0]);
        gld_lds16(u + aoff1, &lds[1][kh][buf][wrow1][0]);
    };

    f32x4 acc[8][4] = {};

    // prologue: prime pipeline; invariant entering t=0:
    // in flight = {(0)Ak1,(0)Bk1,(1)Ak0,(1)Bk0} (8 loads)
    stageA(0, 0, 0); stageB(0, 0, 0);
    stageA(0, 1, 0); stageB(0, 1, 0);
    stageA(1, 0, 1); stageB(1, 0, 1);
    asm volatile("s_waitcnt vmcnt(8)" ::: "memory");
    __builtin_amdgcn_s_barrier();

    int arow = wr * 128 + lm;
    int brow = wc * 64 + lm;
    int kswz = 8 * (lk ^ ((lm >> 1) & 3));   // T2 read-side swizzled column

#define KBODY(T, BUF) do {                                                             \
    bf16x8 afr[4], bfr[4];                                                             \
    /* Phase 0: ksub 0, m-frags 0..3 (+ B frags ks0) */                                \
    _Pragma("unroll")                                                                  \
    for (int i = 0; i < 4; i++)                                                        \
        afr[i] = *(const bf16x8*)&lds[0][0][BUF][arow + i * 16][kswz];                 \
    _Pragma("unroll")                                                                  \
    for (int j = 0; j < 4; j++)                                                        \
        bfr[j] = *(const bf16x8*)&lds[1][0][BUF][brow + j * 16][kswz];                 \
    if ((T) + 1 < KT_N) stageA((T) + 1, 1, (BUF) ^ 1);                                 \
    __builtin_amdgcn_s_barrier();                                                      \
    asm volatile("s_waitcnt lgkmcnt(0)" ::: "memory");                                 \
    __builtin_amdgcn_sched_barrier(0);                                                 \
    __builtin_amdgcn_s_setprio(1);                                                     \
    _Pragma("unroll")                                                                  \
    for (int i = 0; i < 4; i++)                                                        \
        _Pragma("unroll")                                                              \
        for (int j = 0; j < 4; j++)                                                    \
            acc[i][j] = __builtin_amdgcn_mfma_f32_16x16x32_bf16(afr[i], bfr[j], acc[i][j], 0, 0, 0); \
    __builtin_amdgcn_s_setprio(0);                                                     \
    __builtin_amdgcn_sched_barrier(0);                                                 \
    __builtin_amdgcn_s_barrier();                                                      \
    /* Phase 1: ksub 0, m-frags 4..7 */                                                \
    _Pragma("unroll")                                                                  \
    for (int i = 0; i < 4; i++)                                                        \
        afr[i] = *(const bf16x8*)&lds[0][0][BUF][arow + (i + 4) * 16][kswz];           \
    if ((T) + 1 < KT_N) stageB((T) + 1, 1, (BUF) ^ 1);                                 \
    __builtin_amdgcn_s_barrier();                                                      \
    asm volatile("s_waitcnt lgkmcnt(0)" ::: "memory");                                 \
    __builtin_amdgcn_sched_barrier(0);                                                 \
    __builtin_amdgcn_s_setprio(1);                                                     \
    _Pragma("unroll")                                                                  \
    for (int i = 0; i < 4; i++)                                                        \
        _Pragma("unroll")                                                              \
        for (int j = 0; j < 4; j++)                                                    \
            acc[i + 4][j] = __builtin_amdgcn_mfma_f32_16x16x32_bf16(afr[i], bfr[j], acc[i + 4][j], 0, 0, 0); \
    __builtin_amdgcn_s_setprio(0);                                                     \
    __builtin_amdgcn_sched_barrier(0);                                                 \
    if ((T) + 1 < KT_N) { asm volatile("s_waitcnt vmcnt(8)" ::: "memory"); }           \
    else                { asm volatile("s_waitcnt vmcnt(0)" ::: "memory"); }           \
    __builtin_amdgcn_s_barrier();                                                      \
    /* Phase 2: ksub 1, m-frags 0..3 (+ B frags ks1) */                                \
    _Pragma("unroll")                                                                  \
    for (int i = 0; i < 4; i++)                                                        \
        afr[i] = *(const bf16x8*)&lds[0][1][BUF][arow + i * 16][kswz];                 \
    _Pragma("unroll")                                                                  \
    for (int j = 0; j < 4; j++)                                                        \
        bfr[j] = *(const bf16x8*)&lds[1][1][BUF][brow + j * 16][kswz];                 \
    if ((T) + 2 < KT_N) stageA((T) + 2, 0, BUF);                                       \
    __builtin_amdgcn_s_barrier();                                                      \
    asm volatile("s_waitcnt lgkmcnt(0)" ::: "memory");                                 \
    __builtin_amdgcn_sched_barrier(0);                                                 \
    __builtin_amdgcn_s_setprio(1);                                                     \
    _Pragma("unroll")                                                                  \
    for (int i = 0; i < 4; i++)                                                        \
        _Pragma("unroll")                                                              \
        for (int j = 0; j < 4; j++)                                                    \
            acc[i][j] = __builtin_amdgcn_mfma_f32_16x16x32_bf16(afr[i], bfr[j], acc[i][j], 0, 0, 0); \
    __builtin_amdgcn_s_setprio(0);                                                     \
    __builtin_amdgcn_sched_barrier(0);                                                 \
    __builtin_amdgcn_s_barrier();                                                      \
    /* Phase 3: ksub 1, m-frags 4..7 */                                                \
    _Pragma("unroll")                                                                  \
    for (int i = 0; i < 4; i++)                                                        \
        afr[i] = *(const bf16x8*)&lds[0][1][BUF][arow + (i + 4) * 16][kswz];           \
    if ((T) + 2 < KT_N) stageB((T) + 2, 0, BUF);                                       \
    __builtin_amdgcn_s_barrier();                                                      \
    asm volatile("s_waitcnt lgkmcnt(0)" ::: "memory");                                 \
    __builtin_amdgcn_sched_barrier(0);                                                 \
    __builtin_amdgcn_s_setprio(1);                                                     \
    _Pragma("unroll")                                                                  \
    for (int i = 0; i < 4; i++)                                                        \
        _Pragma("unroll")                                                              \
        for (int j = 0; j < 4; j++)                                                    \
            acc[i + 4][j] = __builtin_amdgcn_mfma_f32_16x16x32_bf16(afr[i], bfr[j], acc[i + 4][j], 0, 0, 0); \
    __builtin_amdgcn_s_setprio(0);                                                     \
    __builtin_amdgcn_sched_barrier(0);                                                 \
    if ((T) + 2 < KT_N)      { asm volatile("s_waitcnt vmcnt(8)" ::: "memory"); }      \
    else if ((T) + 1 < KT_N) { asm volatile("s_waitcnt vmcnt(4)" ::: "memory"); }      \
    __builtin_amdgcn_s_barrier();                                                      \
} while (0)

    for (int u = 0; u < KT_N / 2; ++u) {
        KBODY(2 * u, 0);
        KBODY(2 * u + 1, 1);
    }
#undef KBODY

    // ---- epilogue: C/D layout col=lane&15, row=(lane>>4)*4+reg ----
    if (mode == 0) {
        #pragma unroll
        for (int fm = 0; fm < 8; fm++) {
            int grow0 = m0 + wr * 128 + fm * 16 + lk * 4;
            #pragma unroll
            for (int fn = 0; fn < 4; fn++) {
                int gcol = n0 + wc * 64 + fn * 16 + lm;
                #pragma unroll
                for (int reg = 0; reg < 4; reg++)
                    C0[(size_t)(grow0 + reg) * N + gcol] = acc[fm][fn][reg];
            }
        }
    } else {
        #pragma unroll
        for (int fm = 0; fm < 8; fm++) {
            int grow0 = m0 + wr * 128 + fm * 16 + lk * 4;
            #pragma unroll
            for (int fn = 0; fn < 4; fn++) {
                int n = n0 + wc * 64 + fn * 16 + lm;
                float* dst; int nn;
                if (n < 1024)      { dst = Cq; nn = n; }
                else if (n < 2048) { dst = Ck; nn = n - 1024; }
                else               { dst = Cv; nn = n - 2048; }
                int hh = nn >> 6, d = nn & 63;
                #pragma unroll
                for (int reg = 0; reg < 4; reg++) {
                    int m = grow0 + reg;
                    int b = m >> 12, tt2 = m & 4095;
                    dst[(((size_t)(b * NH + hh)) * SEQ + tt2) * HS + d] = acc[fm][fn][reg];
                }
            }
        }
        // ---- fused landmarks: window(64-row) column means for q/k slices ----
        // rows wr*128 + wsel*64 .. +63 form one complete landmark window.
        int bb = (m0 + wr * 128) >> 12;
        #pragma unroll
        for (int wsel = 0; wsel < 2; wsel++) {
            int mwin = m0 + wr * 128 + wsel * 64;
            int lwin = (mwin >> 6) & 63;
            #pragma unroll
            for (int fn = 0; fn < 4; fn++) {
                float p = 0.f;
                #pragma unroll
                for (int fi = 0; fi < 4; fi++)
                    #pragma unroll
                    for (int reg = 0; reg < 4; reg++)
                        p += acc[wsel * 4 + fi][fn][reg];
                p += __shfl_xor(p, 16, 64);
                p += __shfl_xor(p, 32, 64);
                if (lk == 0) {
                    int n = n0 + wc * 64 + fn * 16 + lm;
                    if (n < 2048) {
                        float* dstl = (n < 1024) ? ql_out : kl_out;
                        int nn = n & 1023;
                        int hh = nn >> 6, d = nn & 63;
                        dstl[(((size_t)(bb * NH + hh)) * 64 + lwin) * 64 + d] = p * (1.0f / 64.0f);
                    }
                }
            }
        }
    }
}

// ---------------- fused: pinv (blocks 0..63) + nv_partial (blocks 64..1087) ----------------
// Independent after gemm8 (both consume only ql/kl/k/v) -> pinv's ~64us serial
// chain hides under nv's throughput. Union LDS = 80KB -> 2 blocks/CU (160KB).
#define NVP 68
__global__ __launch_bounds__(256) void nvpinv(const float* __restrict__ ql,
                                              const float* __restrict__ kl,
                                              const float* __restrict__ k,
                                              const float* __restrict__ v,
                                              float* __restrict__ Pbuf,
                                              float* __restrict__ pm,
                                              float* __restrict__ ps,
                                              float* __restrict__ pacc)
{
    __shared__ __align__(16) float smem[20480];   // 80 KiB union
    int bid = blockIdx.x;
    int tid = threadIdx.x;

    if (bid < 64) {
        // ================= pinv path (bh = bid), pad 64 =================
        int bh = bid;
        float (*AsmT)[64] = (float(*)[64])(smem);
        float (*Vv)[64]   = (float(*)[64])(smem + 4096);
        float (*VT)[64]   = (float(*)[64])(smem + 8192);
        float (*KVT)[64]  = (float(*)[64])(smem + 12288);
        float (*Tb)[64]   = (float(*)[64])(smem + 16384);
        int ri = tid >> 4, cj = tid & 15;
        int r0 = ri * 4, c0 = cj * 4;

        // stage qlT -> Vv, klT -> VT (scratch; overwritten at denom stage)
        {
            int sd = tid & 63, srg = tid >> 6;
            const float* qp = ql + (size_t)bh * 4096;
            const float* kp = kl + (size_t)bh * 4096;
            float bq[16], bk[16];
            #pragma unroll
            for (int j = 0; j < 16; j++) {
                bq[j] = qp[(srg * 16 + j) * 64 + sd];
                bk[j] = kp[(srg * 16 + j) * 64 + sd];
            }
            #pragma unroll
            for (int jj = 0; jj < 4; jj++) {
                f32x4 t1 = { bq[4 * jj], bq[4 * jj + 1], bq[4 * jj + 2], bq[4 * jj + 3] };
                f32x4 t2 = { bk[4 * jj], bk[4 * jj + 1], bk[4 * jj + 2], bk[4 * jj + 3] };
                *(f32x4*)&Vv[sd][srg * 16 + 4 * jj] = t1;
                *(f32x4*)&VT[sd][srg * 16 + 4 * jj] = t2;
            }
        }
        __syncthreads();

        // scores S = ql @ kl^T
        float c[4][4] = {};
        for (int d = 0; d < 64; d++) {
            f32x4 a = *(const f32x4*)&Vv[d][r0];
            f32x4 b = *(const f32x4*)&VT[d][c0];
            #pragma unroll
            for (int i = 0; i < 4; i++)
                #pragma unroll
                for (int j = 0; j < 4; j++) c[i][j] += a[i] * b[j];
        }
        #pragma unroll
        for (int i = 0; i < 4; i++) {
            float tmax = fmaxf(fmaxf(c[i][0], c[i][1]), fmaxf(c[i][2], c[i][3]));
            #pragma unroll
            for (int off = 1; off < 16; off <<= 1)
                tmax = fmaxf(tmax, __shfl_xor(tmax, off, 64));
            float psum = 0.f;
            #pragma unroll
            for (int j = 0; j < 4; j++) {
                float p = expf(c[i][j] - tmax);
                c[i][j] = p; psum += p;
            }
            #pragma unroll
            for (int off = 1; off < 16; off <<= 1)
                psum += __shfl_xor(psum, off, 64);
            float inv = 1.0f / psum;
            #pragma unroll
            for (int j = 0; j < 4; j++) c[i][j] *= inv;
        }
        __syncthreads();
        #pragma unroll
        for (int j = 0; j < 4; j++) {
            f32x4 t = { c[0][j], c[1][j], c[2][j], c[3][j] };
            *(f32x4*)&AsmT[c0 + j][r0] = t;
        }
        __syncthreads();

        // denom = max over columns of column sums (wave0 shfl reduce)
        if (tid < 64) {
            float cs = 0.f;
            for (int x = 0; x < 64; x += 4) {
                f32x4 t = *(const f32x4*)&AsmT[tid][x];
                cs += t[0] + t[1] + t[2] + t[3];
            }
            #pragma unroll
            for (int off = 1; off < 64; off <<= 1)
                cs = fmaxf(cs, __shfl_xor(cs, off, 64));
            if (tid == 0) Tb[0][0] = cs;
        }
        __syncthreads();
        float dinv = 1.0f / Tb[0][0];
        __syncthreads();
        #pragma unroll
        for (int i = 0; i < 4; i++) {
            f32x4 t = *(const f32x4*)&AsmT[r0 + i][c0];
            f32x4 o = t * dinv;
            *(f32x4*)&Vv[r0 + i][c0] = o;
        }
        #pragma unroll
        for (int j = 0; j < 4; j++) {
            f32x4 t = { AsmT[r0 + 0][c0 + j] * dinv, AsmT[r0 + 1][c0 + j] * dinv,
                        AsmT[r0 + 2][c0 + j] * dinv, AsmT[r0 + 3][c0 + j] * dinv };
            *(f32x4*)&VT[c0 + j][r0] = t;
        }
        __syncthreads();

        float u[4][4];
        for (int it = 0; it < 6; it++) {
            // M1: KV = Asm @ V (KVT + Tb written; KV itself never materialized)
            #pragma unroll
            for (int i = 0; i < 4; i++)
                #pragma unroll
                for (int j = 0; j < 4; j++) c[i][j] = 0.f;
            for (int kx = 0; kx < 64; kx++) {
                f32x4 a = *(const f32x4*)&AsmT[kx][r0];
                f32x4 b = *(const f32x4*)&Vv[kx][c0];
                #pragma unroll
                for (int i = 0; i < 4; i++)
                    #pragma unroll
                    for (int j = 0; j < 4; j++) c[i][j] += a[i] * b[j];
            }
            __syncthreads();
            #pragma unroll
            for (int j = 0; j < 4; j++) {
                f32x4 t = { c[0][j], c[1][j], c[2][j], c[3][j] };
                *(f32x4*)&KVT[c0 + j][r0] = t;
            }
            #pragma unroll
            for (int i = 0; i < 4; i++) {
                f32x4 t;
                #pragma unroll
                for (int j = 0; j < 4; j++)
                    t[j] = ((r0 + i) == (c0 + j) ? 7.0f : 0.0f) - c[i][j];
                *(f32x4*)&Tb[r0 + i][c0] = t;
            }
            __syncthreads();
            // M2: U = KV @ T1 -> T2
            #pragma unroll
            for (int i = 0; i < 4; i++)
                #pragma unroll
                for (int j = 0; j < 4; j++) u[i][j] = 0.f;
            for (int kx = 0; kx < 64; kx++) {
                f32x4 a = *(const f32x4*)&KVT[kx][r0];
                f32x4 b = *(const f32x4*)&Tb[kx][c0];
                #pragma unroll
                for (int i = 0; i < 4; i++)
                    #pragma unroll
                    for (int j = 0; j < 4; j++) u[i][j] += a[i] * b[j];
            }
            __syncthreads();
            #pragma unroll
            for (int i = 0; i < 4; i++) {
                f32x4 t;
                #pragma unroll
                for (int j = 0; j < 4; j++)
                    t[j] = ((r0 + i) == (c0 + j) ? 15.0f : 0.0f) - u[i][j];
                *(f32x4*)&Tb[r0 + i][c0] = t;
            }
            __syncthreads();
            // M3: U2 = KV @ T2 -> T3
            #pragma unroll
            for (int i = 0; i < 4; i++)
                #pragma unroll
                for (int j = 0; j < 4; j++) u[i][j] = 0.f;
            for (int kx = 0; kx < 64; kx++) {
                f32x4 a = *(const f32x4*)&KVT[kx][r0];
                f32x4 b = *(const f32x4*)&Tb[kx][c0];
                #pragma unroll
                for (int i = 0; i < 4; i++)
                    #pragma unroll
                    for (int j = 0; j < 4; j++) u[i][j] += a[i] * b[j];
            }
            __syncthreads();
            #pragma unroll
            for (int i = 0; i < 4; i++) {
                f32x4 t;
                #pragma unroll
                for (int j = 0; j < 4; j++)
                    t[j] = ((r0 + i) == (c0 + j) ? 13.0f : 0.0f) - u[i][j];
                *(f32x4*)&Tb[r0 + i][c0] = t;
            }
            __syncthreads();
            // M4: Vn = 0.25 * V @ T3
            #pragma unroll
            for (int i = 0; i < 4; i++)
                #pragma unroll
                for (int j = 0; j < 4; j++) c[i][j] = 0.f;
            for (int kx = 0; kx < 64; kx++) {
                f32x4 a = *(const f32x4*)&VT[kx][r0];
                f32x4 b = *(const f32x4*)&Tb[kx][c0];
                #pragma unroll
                for (int i = 0; i < 4; i++)
                    #pragma unroll
                    for (int j = 0; j < 4; j++) c[i][j] += a[i] * b[j];
            }
            __syncthreads();
            #pragma unroll
            for (int i = 0; i < 4; i++) {
                f32x4 o;
                #pragma unroll
                for (int j = 0; j < 4; j++) o[j] = 0.25f * c[i][j];
                *(f32x4*)&Vv[r0 + i][c0] = o;
            }
            #pragma unroll
            for (int j = 0; j < 4; j++) {
                f32x4 t = { 0.25f * c[0][j], 0.25f * c[1][j], 0.25f * c[2][j], 0.25f * c[3][j] };
                *(f32x4*)&VT[c0 + j][r0] = t;
            }
            __syncthreads();
        }
        #pragma unroll
        for (int i = 0; i < 4; i++)
            *(f32x4*)&Pbuf[(size_t)bh * 4096 + (r0 + i) * 64 + c0] = *(const f32x4*)&Vv[r0 + i][c0];
    } else {
        // ================= nv_partial path =================
        int idx = bid - 64;
        int bh = idx >> 4;
        int c0 = idx & 15;
        int rg = tid >> 4, tg = tid & 15;
        int sd = tid & 63, srg = tid >> 6;
        float (*qlT)[NVP] = (float(*)[NVP])(smem);
        float (*kT)[NVP]  = (float(*)[NVP])(smem + 4352);
        float (*vch)[NVP] = (float(*)[NVP])(smem + 8704);
        float (*pchT)[NVP]= (float(*)[NVP])(smem + 13056);

        {
            const float* qp = ql + (size_t)bh * 4096;
            float bq[16];
            #pragma unroll
            for (int j = 0; j < 16; j++) bq[j] = qp[(srg * 16 + j) * 64 + sd];
            #pragma unroll
            for (int jj = 0; jj < 4; jj++) {
                f32x4 t = { bq[4 * jj], bq[4 * jj + 1], bq[4 * jj + 2], bq[4 * jj + 3] };
                *(f32x4*)&qlT[sd][srg * 16 + 4 * jj] = t;
            }
        }

        float m_r[4], s_r[4];
        float acc[4][4];
        #pragma unroll
        for (int i = 0; i < 4; i++) {
            m_r[i] = -1e30f; s_r[i] = 0.f;
            #pragma unroll
            for (int j = 0; j < 4; j++) acc[i][j] = 0.f;
        }

        for (int sc = 0; sc < 4; sc++) {
            __syncthreads();
            const float* kp = k + ((size_t)bh * SEQ + c0 * 256 + sc * 64) * HS;
            const float* vp = v + ((size_t)bh * SEQ + c0 * 256 + sc * 64) * HS;
            {
                float bk[16];
                #pragma unroll
                for (int j = 0; j < 16; j++) bk[j] = kp[(srg * 16 + j) * 64 + sd];
                #pragma unroll
                for (int jj = 0; jj < 4; jj++) {
                    f32x4 t = { bk[4 * jj], bk[4 * jj + 1], bk[4 * jj + 2], bk[4 * jj + 3] };
                    *(f32x4*)&kT[sd][srg * 16 + 4 * jj] = t;
                }
            }
            for (int i = tid; i < 4096; i += 256)
                vch[i >> 6][i & 63] = vp[i];
            __syncthreads();

            float s[4][4] = {};
            #pragma unroll 4
            for (int dd = 0; dd < 64; dd++) {
                f32x4 a = *(const f32x4*)&qlT[dd][rg * 4];
                f32x4 b = *(const f32x4*)&kT[dd][tg * 4];
                #pragma unroll
                for (int i = 0; i < 4; i++)
                    #pragma unroll
                    for (int j = 0; j < 4; j++) s[i][j] += a[i] * b[j];
            }

            #pragma unroll
            for (int i = 0; i < 4; i++) {
                float tmax = fmaxf(fmaxf(s[i][0], s[i][1]), fmaxf(s[i][2], s[i][3]));
                #pragma unroll
                for (int off = 1; off < 16; off <<= 1)
                    tmax = fmaxf(tmax, __shfl_xor(tmax, off, 64));
                float mnew = fmaxf(m_r[i], tmax);
                float alpha = expf(m_r[i] - mnew);
                m_r[i] = mnew;
                float psum = 0.f;
                #pragma unroll
                for (int j = 0; j < 4; j++) {
                    float p = expf(s[i][j] - mnew);
                    s[i][j] = p;
                    psum += p;
                }
                #pragma unroll
                for (int off = 1; off < 16; off <<= 1)
                    psum += __shfl_xor(psum, off, 64);
                s_r[i] = s_r[i] * alpha + psum;
                #pragma unroll
                for (int j = 0; j < 4; j++) acc[i][j] *= alpha;
            }
            #pragma unroll
            for (int j = 0; j < 4; j++) {
                f32x4 t = { s[0][j], s[1][j], s[2][j], s[3][j] };
                *(f32x4*)&pchT[tg * 4 + j][rg * 4] = t;
            }
            __syncthreads();

            #pragma unroll 2
            for (int tt = 0; tt < 64; tt++) {
                f32x4 vv = *(const f32x4*)&vch[tt][tg * 4];
                f32x4 pr = *(const f32x4*)&pchT[tt][rg * 4];
                #pragma unroll
                for (int i = 0; i < 4; i++)
                    #pragma unroll
                    for (int j = 0; j < 4; j++)
                        acc[i][j] += pr[i] * vv[j];
            }
        }

        float* paccp = pacc + ((((size_t)bh * 16 + c0) * 64) + rg * 4) * 64 + tg * 4;
        #pragma unroll
        for (int i = 0; i < 4; i++)
            *(f32x4*)&paccp[(size_t)i * 64] = *(f32x4*)&acc[i][0];
        if (tg == 0) {
            #pragma unroll
            for (int i = 0; i < 4; i++) {
                pm[((size_t)bh * 16 + c0) * 64 + rg * 4 + i] = m_r[i];
                ps[((size_t)bh * 16 + c0) * 64 + rg * 4 + i] = s_r[i];
            }
        }
    }
}

// ---------------- N path phase 2 + PNv, fused: Nv in LDS, PNv = P @ Nv ----------------
__global__ __launch_bounds__(256) void combine_pnv(const float* __restrict__ pm,
                                                   const float* __restrict__ ps,
                                                   const float* __restrict__ pacc,
                                                   const float* __restrict__ P,
                                                   float* __restrict__ PNv)
{
    int bh = blockIdx.x;
    int tid = threadIdx.x;
    __shared__ float NvS[64][NVP];
    __shared__ float PT[64][NVP];

    // stage P transposed (conflict-free)
    {
        int sd = tid & 63, srg = tid >> 6;
        const float* pb = P + (size_t)bh * 4096;
        float bp[16];
        #pragma unroll
        for (int j = 0; j < 16; j++) bp[j] = pb[(srg * 16 + j) * 64 + sd];
        #pragma unroll
        for (int jj = 0; jj < 4; jj++) {
            f32x4 t = { bp[4 * jj], bp[4 * jj + 1], bp[4 * jj + 2], bp[4 * jj + 3] };
            *(f32x4*)&PT[sd][srg * 16 + 4 * jj] = t;
        }
    }

    // combine 16 chunk partials -> Nv row in LDS
    {
        int l = tid >> 2, dq = tid & 3;
        float m16[16];
        float gm = -1e30f;
        #pragma unroll
        for (int c = 0; c < 16; c++) {
            m16[c] = pm[((size_t)bh * 16 + c) * 64 + l];
            gm = fmaxf(gm, m16[c]);
        }
        float gs = 0.f;
        float e16[16];
        #pragma unroll
        for (int c = 0; c < 16; c++) {
            float e = expf(m16[c] - gm);
            e16[c] = e;
            gs += ps[((size_t)bh * 16 + c) * 64 + l] * e;
        }
        f32x4 a[4] = {};
        for (int c = 0; c < 16; c++) {
            float e = e16[c];
            const float* pp = pacc + (((size_t)bh * 16 + c) * 64 + l) * 64 + dq * 16;
            #pragma unroll
            for (int i = 0; i < 4; i++) {
                f32x4 t = *(const f32x4*)&pp[4 * i];
                a[i] += e * t;
            }
        }
        float inv = 1.0f / gs;
        #pragma unroll
        for (int i = 0; i < 4; i++) {
            f32x4 o = a[i] * inv;
            *(f32x4*)&NvS[l][dq * 16 + 4 * i] = o;
        }
    }
    __syncthreads();

    // PNv = P @ Nv (4x4 register tiles)
    int ri = tid >> 4, cj = tid & 15;
    int r0 = ri * 4, c0 = cj * 4;
    float c[4][4] = {};
    for (int kx = 0; kx < 64; kx++) {
        f32x4 a = *(const f32x4*)&PT[kx][r0];
        f32x4 b = *(const f32x4*)&NvS[kx][c0];
        #pragma unroll
        for (int i = 0; i < 4; i++)
            #pragma unroll
            for (int j = 0; j < 4; j++) c[i][j] += a[i] * b[j];
    }
    #pragma unroll
    for (int i = 0; i < 4; i++)
        *(f32x4*)&PNv[(size_t)bh * 4096 + (r0 + i) * 64 + c0] = *(f32x4*)&c[i][0];
}

// ---------------- y = softmax(q @ kl^T) @ PNv -> hi/lo bf16 (B,T,C) ----------------
__global__ __launch_bounds__(256) void y_kernel(const float* __restrict__ q,
                                                const float* __restrict__ kl,
                                                const float* __restrict__ PNv,
                                                bf16_t* __restrict__ yhi,
                                                bf16_t* __restrict__ ylo)
{
    int bh = blockIdx.y;
    int t0 = blockIdx.x * 64;
    int tid = threadIdx.x;
    __shared__ float qT[64][NVP], klT[64][NVP], pnv[64][NVP], pT[64][NVP];
    const float* qp = q + ((size_t)bh * SEQ + t0) * HS;
    const float* kp = kl + (size_t)bh * 4096;
    const float* pp = PNv + (size_t)bh * 4096;
    {
        int sd = tid & 63, srg = tid >> 6;
        float bq[16], bk[16];
        #pragma unroll
        for (int j = 0; j < 16; j++) {
            bq[j] = qp[(srg * 16 + j) * 64 + sd];
            bk[j] = kp[(srg * 16 + j) * 64 + sd];
        }
        #pragma unroll
        for (int jj = 0; jj < 4; jj++) {
            f32x4 t1 = { bq[4 * jj], bq[4 * jj + 1], bq[4 * jj + 2], bq[4 * jj + 3] };
            f32x4 t2 = { bk[4 * jj], bk[4 * jj + 1], bk[4 * jj + 2], bk[4 * jj + 3] };
            *(f32x4*)&qT[sd][srg * 16 + 4 * jj]  = t1;
            *(f32x4*)&klT[sd][srg * 16 + 4 * jj] = t2;
        }
        for (int i = tid; i < 4096; i += 256)
            pnv[i >> 6][i & 63] = pp[i];
    }
    __syncthreads();

    int ti = tid >> 4, gj = tid & 15;
    int r0 = ti * 4, c0 = gj * 4;

    // scores S[4t][4l]
    float s[4][4] = {};
    for (int d = 0; d < 64; d++) {
        f32x4 a = *(const f32x4*)&qT[d][r0];
        f32x4 b = *(const f32x4*)&klT[d][c0];
        #pragma unroll
        for (int i = 0; i < 4; i++)
            #pragma unroll
            for (int j = 0; j < 4; j++) s[i][j] += a[i] * b[j];
    }
    // row softmax across 16-lane gj group
    #pragma unroll
    for (int i = 0; i < 4; i++) {
        float tmax = fmaxf(fmaxf(s[i][0], s[i][1]), fmaxf(s[i][2], s[i][3]));
        #pragma unroll
        for (int off = 1; off < 16; off <<= 1)
            tmax = fmaxf(tmax, __shfl_xor(tmax, off, 64));
        float psum = 0.f;
        #pragma unroll
        for (int j = 0; j < 4; j++) {
            float p = expf(s[i][j] - tmax);
            s[i][j] = p; psum += p;
        }
        #pragma unroll
        for (int off = 1; off < 16; off <<= 1)
            psum += __shfl_xor(psum, off, 64);
        float inv = 1.0f / psum;
        #pragma unroll
        for (int j = 0; j < 4; j++) s[i][j] *= inv;
    }
    #pragma unroll
    for (int j = 0; j < 4; j++) {
        f32x4 t = { s[0][j], s[1][j], s[2][j], s[3][j] };
        *(f32x4*)&pT[c0 + j][r0] = t;
    }
    __syncthreads();

    // PV: out[4t][4d], d-cols c0..
    float o[4][4] = {};
    for (int l = 0; l < 64; l++) {
        f32x4 a = *(const f32x4*)&pT[l][r0];
        f32x4 b = *(const f32x4*)&pnv[l][c0];
        #pragma unroll
        for (int i = 0; i < 4; i++)
            #pragma unroll
            for (int j = 0; j < 4; j++) o[i][j] += a[i] * b[j];
    }

    int b = bh >> 4, h = bh & 15;
    #pragma unroll
    for (int i = 0; i < 4; i++) {
        bf16x4 hv, lv;
        #pragma unroll
        for (int j = 0; j < 4; j++) {
            float v = o[i][j];
            bf16_t hh = (bf16_t)v;
            hv[j] = hh;
            lv[j] = (bf16_t)(v - (float)hh);
        }
        size_t oo = ((size_t)(b * SEQ) + t0 + r0 + i) * CDIM + h * HS + c0;
        *(bf16x4*)(yhi + oo) = hv;
        *(bf16x4*)(ylo + oo) = lv;
    }
}

// ---------------- launch ----------------
extern "C" void kernel_launch(void* const* d_in, const int* in_sizes, int n_in,
                              void* d_out, int out_size, void* d_ws, size_t ws_size,
                              hipStream_t stream)
{
    const float* x  = (const float*)d_in[0];
    const float* Wa = (const float*)d_in[1];
    const float* Wp = (const float*)d_in[2];
    float* out = (float*)d_out;
    float* W = (float*)d_ws;

    const size_t off_q    = 0;
    const size_t off_k    = 16777216;
    const size_t off_v    = 33554432;
    const size_t off_ql   = 50331648;
    const size_t off_kl   = off_ql + 262144;
    const size_t off_P    = off_kl + 262144;
    const size_t off_Nv   = off_P  + 262144;
    const size_t off_PNv  = off_Nv + 262144;
    const size_t off_WatH = off_PNv + 262144;
    const size_t off_WatL = off_WatH + 1572864;
    const size_t off_WptH = off_WatL + 1572864;
    const size_t off_WptL = off_WptH + 524288;
    const size_t off_pm   = off_WptL + 524288;
    const size_t off_ps   = off_pm + 65536;
    const size_t off_pacc = off_ps + 65536;
    const size_t need = (off_pacc + 4194304) * sizeof(float);
    if (ws_size < need) {
        fprintf(stderr, "[nystrom] ws too small: have %zu need %zu\n", ws_size, need);
        return;
    }

    float* q    = W + off_q;
    float* k    = W + off_k;
    float* v    = W + off_v;
    float* ql   = W + off_ql;
    float* kl   = W + off_kl;
    float* P    = W + off_P;
    float* PNv  = W + off_PNv;
    bf16_t* WatH = (bf16_t*)(W + off_WatH);
    bf16_t* WatL = (bf16_t*)(W + off_WatL);
    bf16_t* WptH = (bf16_t*)(W + off_WptH);
    bf16_t* WptL = (bf16_t*)(W + off_WptL);
    float* pm   = W + off_pm;
    float* ps   = W + off_ps;
    float* pacc = W + off_pacc;
    bf16_t* yhi = (bf16_t*)(W + off_k);       // alias k (dead after nvpinv)
    bf16_t* ylo = yhi + (size_t)MROWS * CDIM;
    bf16_t* xhi = (bf16_t*)d_out;             // d_out scratch until final GEMM
    bf16_t* xlo = xhi + (size_t)MROWS * KDIM;

    transpose_split<<<dim3(N3 / 64, KDIM / 64), 256, 0, stream>>>(Wa, WatH, WatL, KDIM, N3);
    transpose_split<<<dim3(CDIM / 64, KDIM / 64), 256, 0, stream>>>(Wp, WptH, WptL, KDIM, CDIM);
    split_x<<<(MROWS * KDIM) / (256 * 8), 256, 0, stream>>>(x, xhi, xlo);
    gemm8<<<dim3(N3 / 256, MROWS / 256), 512, 0, stream>>>(xhi, xlo, WatH, WatL,
                                                           nullptr, q, k, v, ql, kl, N3, 1);
    nvpinv<<<1088, 256, 0, stream>>>(ql, kl, k, v, P, pm, ps, pacc);
    combine_pnv<<<64, 256, 0, stream>>>(pm, ps, pacc, P, PNv);
    y_kernel<<<dim3(64, 64), 256, 0, stream>>>(q, kl, PNv, yhi, ylo);
    gemm8<<<dim3(CDIM / 256, MROWS / 256), 512, 0, stream>>>(yhi, ylo, WptH, WptL,
                                                             out, nullptr, nullptr, nullptr,
                                                             nullptr, nullptr, CDIM, 0);
}